// Round 17
// baseline (263.709 us; speedup 1.0000x reference)
//
#include <hip/hip_runtime.h>
#include <hip/hip_bf16.h>
#include <stdint.h>

#define NTOK 32768
#define DIM  768
#define HID  256
#define NEXP 8
#define PADC 144   // repack-tile column pad: conflict-reduced epilogue writes

typedef float f32x4 __attribute__((ext_vector_type(4)));
typedef short s16x8 __attribute__((ext_vector_type(8)));

__device__ __forceinline__ unsigned short f2bf(float f) {
  union { float f; unsigned int u; } c; c.f = f;
  unsigned int r = c.u + 0x7fffu + ((c.u >> 16) & 1u);
  return (unsigned short)(r >> 16);
}

__device__ __forceinline__ float bf2f(unsigned int u) {
  union { unsigned int x; float f; } c; c.x = u << 16; return c.f;
}

__device__ __forceinline__ unsigned short f2h(float f) {
  union { _Float16 h; unsigned short u; } c; c.h = (_Float16)f; return c.u;
}

__device__ __forceinline__ float h2f(unsigned short u) {
  union { unsigned short u; _Float16 h; } c; c.u = u; return (float)c.h;
}

// async global -> LDS, 16B per lane. LDS dest is wave-uniform base + lane*16.
__device__ __forceinline__ void gload_lds16(const unsigned short* g, unsigned short* l) {
  __builtin_amdgcn_global_load_lds((const __attribute__((address_space(1))) void*)g,
                                   (__attribute__((address_space(3))) void*)l, 16, 0, 0);
}

// ---------------- x fp32 -> fp16 (gate + experts) ----------------
__global__ __launch_bounds__(256) void k_cvt_x(const float* __restrict__ x,
                                               unsigned short* __restrict__ xf16) {
  int i = (blockIdx.x * 256 + threadIdx.x) * 8;
  float4 a = *(const float4*)(x + i);
  float4 b = *(const float4*)(x + i + 4);
  float f[8] = {a.x, a.y, a.z, a.w, b.x, b.y, b.z, b.w};
  unsigned short hh[8];
#pragma unroll
  for (int q = 0; q < 8; ++q) hh[q] = f2h(f[q]);
  int4 vh;
  vh.x = (int)((unsigned)hh[0] | ((unsigned)hh[1] << 16));
  vh.y = (int)((unsigned)hh[2] | ((unsigned)hh[3] << 16));
  vh.z = (int)((unsigned)hh[4] | ((unsigned)hh[5] << 16));
  vh.w = (int)((unsigned)hh[6] | ((unsigned)hh[7] << 16));
  *(int4*)(xf16 + i) = vh;
}

// ---------------- fp32 [R][C] -> fp16 [C][R] transpose via LDS tile (per-e slab) ----------------
__global__ __launch_bounds__(256) void k_trh(const float* __restrict__ in,
                                             unsigned short* __restrict__ outp,
                                             int R, int C) {
  __shared__ float tile[32][33];
  int e = blockIdx.z;
  const float* ip = in + (size_t)e * R * C;
  unsigned short* op = outp + (size_t)e * R * C;
  int tx = threadIdx.x & 31, ty = threadIdx.x >> 5;  // 32x8
  int r0 = blockIdx.y * 32, c0 = blockIdx.x * 32;
#pragma unroll
  for (int i = 0; i < 4; ++i)
    tile[ty + i * 8][tx] = ip[(size_t)(r0 + ty + i * 8) * C + c0 + tx];
  __syncthreads();
#pragma unroll
  for (int i = 0; i < 4; ++i)
    op[(size_t)(c0 + ty + i * 8) * R + r0 + tx] = f2h(tile[tx][ty + i * 8]);
}

// ---------------- gate layer 1, fp16 MFMA: hg(fp16) = relu(x @ Wg1 + bg1) ----------------
__global__ __launch_bounds__(256) void k_gmfma(const unsigned short* __restrict__ xh,
                                               const unsigned short* __restrict__ wh,
                                               const float* __restrict__ bg1,
                                               unsigned short* __restrict__ hg) {
  int bm = blockIdx.x * 128;
  int bn = blockIdx.y * 128;

  __shared__ __align__(16) unsigned short Ah[128 * 64];
  __shared__ __align__(16) unsigned short Bh[128 * 64];

  int tid = threadIdx.x;
  int lane = tid & 63;
  int wid = tid >> 6;
  int wm = wid >> 1, wn = wid & 1;
  int ar = lane & 15, kg = lane >> 4;

  const unsigned short *sah[4], *sbh[4];
  unsigned short *dA[4], *dB[4];
#pragma unroll
  for (int i = 0; i < 4; ++i) {
    int cb0 = i * 256 + wid * 64;        // wave-uniform chunk base
    int ci = cb0 + lane;
    int row = ci >> 3;
    int cb = (ci & 7) ^ (row & 7);       // inverse-swizzled source chunk
    sah[i] = xh + (size_t)(bm + row) * DIM + cb * 8;
    sbh[i] = wh + (size_t)(bn + row) * DIM + cb * 8;
    dA[i] = &Ah[cb0 * 8];
    dB[i] = &Bh[cb0 * 8];
  }

  f32x4 acc[4][4] = {};

  for (int kt = 0; kt < DIM / 64; ++kt) {
#pragma unroll
    for (int i = 0; i < 4; ++i) {
      gload_lds16(sah[i] + kt * 64, dA[i]);
      gload_lds16(sbh[i] + kt * 64, dB[i]);
    }
    __syncthreads();
#pragma unroll
    for (int ks = 0; ks < 2; ++ks) {
      int kc = ks * 4 + kg;
      s16x8 a[4], b[4];
#pragma unroll
      for (int m = 0; m < 4; ++m) {
        int row = wm * 64 + m * 16 + ar;
        a[m] = *(const s16x8*)&Ah[row * 64 + ((kc ^ (row & 7)) * 8)];
      }
#pragma unroll
      for (int n = 0; n < 4; ++n) {
        int row = wn * 64 + n * 16 + ar;
        b[n] = *(const s16x8*)&Bh[row * 64 + ((kc ^ (row & 7)) * 8)];
      }
#pragma unroll
      for (int m = 0; m < 4; ++m)
#pragma unroll
        for (int n = 0; n < 4; ++n)
          acc[m][n] = __builtin_amdgcn_mfma_f32_16x16x32_f16(a[m], b[n], acc[m][n], 0, 0, 0);
    }
    __syncthreads();
  }

  // bias + relu -> hg fp16
#pragma unroll
  for (int n = 0; n < 4; ++n) {
    int col = bn + wn * 64 + n * 16 + ar;
    float bb = bg1[col];
#pragma unroll
    for (int m = 0; m < 4; ++m) {
      int rbase = bm + wm * 64 + m * 16 + kg * 4;
#pragma unroll
      for (int r = 0; r < 4; ++r)
        hg[(size_t)(rbase + r) * HID + col] = f2h(fmaxf(acc[m][n][r] + bb, 0.f));
    }
  }
}

// ---------------- gate 2a: scores from hg(fp16) -> gs; flag near-ties for fp32 rescue ----------------
__global__ __launch_bounds__(256) void k_gate2a(const unsigned short* __restrict__ hg,
                                                const float* __restrict__ wg2,
                                                const float* __restrict__ bg2,
                                                float* __restrict__ gs,
                                                int* __restrict__ rcnt,
                                                int* __restrict__ rlist) {
  int tok = blockIdx.x * 256 + threadIdx.x;
  const unsigned short* hrow = hg + (size_t)tok * HID;

  float s[8];
#pragma unroll
  for (int e = 0; e < 8; ++e) s[e] = bg2[e];
#pragma unroll 4
  for (int j = 0; j < 32; ++j) {
    s16x8 hv8 = *(const s16x8*)(hrow + j * 8);
#pragma unroll
    for (int i = 0; i < 8; ++i) {
      float hv = h2f((unsigned short)hv8[i]);
      const float* wr = wg2 + (j * 8 + i) * 8;
#pragma unroll
      for (int e = 0; e < 8; ++e) s[e] += hv * wr[e];
    }
  }

  f32x4 o0 = {s[0], s[1], s[2], s[3]};
  f32x4 o1 = {s[4], s[5], s[6], s[7]};
  *(f32x4*)&gs[(size_t)tok * 8] = o0;
  *(f32x4*)&gs[(size_t)tok * 8 + 4] = o1;

  // top-3 scan; fp16-gate score-gap error sigma ~1e-4. 1e-3 threshold = 10 sigma.
  float m1 = -3e38f, m2 = -3e38f, m3 = -3e38f;
#pragma unroll
  for (int e = 0; e < 8; ++e) {
    float v = s[e];
    if (v > m1)      { m3 = m2; m2 = m1; m1 = v; }
    else if (v > m2) { m3 = m2; m2 = v; }
    else if (v > m3) { m3 = v; }
  }
  if (m2 - m3 < 1e-3f) {
    int i = atomicAdd(rcnt, 1);
    rlist[i] = tok;
  }
}

// ---------------- rescue: exact fp32 gate recompute for flagged tokens ----------------
__global__ __launch_bounds__(256) void k_rescue(const float* __restrict__ x,
                                                const float* __restrict__ wg1,
                                                const float* __restrict__ bg1,
                                                const float* __restrict__ wg2,
                                                const float* __restrict__ bg2,
                                                const int* __restrict__ rcnt,
                                                const int* __restrict__ rlist,
                                                float* __restrict__ gs) {
  __shared__ float xs[DIM];
  __shared__ float ps[4][8];
  int n = rcnt[0];
  int tid = threadIdx.x;
  int lane = tid & 63, wid = tid >> 6;
  for (int idx = blockIdx.x; idx < n; idx += 2048) {
    int tok = rlist[idx];
    __syncthreads();  // protect xs/ps reuse across iterations
#pragma unroll
    for (int q = 0; q < 3; ++q) xs[tid + q * 256] = x[(size_t)tok * DIM + tid + q * 256];
    __syncthreads();
    const float* wcol = wg1 + tid;               // tid = hidden unit (HID==256)
    float pa[8] = {};
#pragma unroll 4
    for (int k0 = 0; k0 < DIM; k0 += 8) {
#pragma unroll
      for (int q = 0; q < 8; ++q)
        pa[q] = fmaf(xs[k0 + q], wcol[(size_t)(k0 + q) * HID], pa[q]);
    }
    float acc = bg1[tid] +
                (((pa[0] + pa[1]) + (pa[2] + pa[3])) + ((pa[4] + pa[5]) + (pa[6] + pa[7])));
    float hj = fmaxf(acc, 0.f);
    float p[8];
#pragma unroll
    for (int e = 0; e < 8; ++e) p[e] = hj * wg2[tid * 8 + e];
#pragma unroll
    for (int off = 32; off >= 1; off >>= 1) {
#pragma unroll
      for (int e = 0; e < 8; ++e) p[e] += __shfl_xor(p[e], off);
    }
    if (lane == 0) {
#pragma unroll
      for (int e = 0; e < 8; ++e) ps[wid][e] = p[e];
    }
    __syncthreads();
    if (tid < 8)
      gs[(size_t)tok * 8 + tid] = bg2[tid] + ps[0][tid] + ps[1][tid] + ps[2][tid] + ps[3][tid];
  }
}

// ---------------- gate 2b: softmax + top2 + routing lists from gs ----------------
__global__ __launch_bounds__(256) void k_gate2b(const float* __restrict__ gs,
                                                float* __restrict__ gprob,
                                                int* __restrict__ cnt,     // stride 32
                                                int* __restrict__ lists,
                                                float* __restrict__ wts) {
  __shared__ int lcnt[8];
  __shared__ int sbase[8];
  __shared__ int se1[256], se2[256], sp1[256], sp2[256];
  __shared__ float sw1[256], sw2[256];
  int tid = threadIdx.x;
  if (tid < 8) lcnt[tid] = 0;
  __syncthreads();

  int tok = blockIdx.x * 256 + tid;
  f32x4 s0v = *(const f32x4*)&gs[(size_t)tok * 8];
  f32x4 s1v = *(const f32x4*)&gs[(size_t)tok * 8 + 4];
  float s[8] = {s0v[0], s0v[1], s0v[2], s0v[3], s1v[0], s1v[1], s1v[2], s1v[3]};

  float m = s[0];
#pragma unroll
  for (int e = 1; e < 8; ++e) m = fmaxf(m, s[e]);
  float p[8]; float sum = 0.f;
#pragma unroll
  for (int e = 0; e < 8; ++e) { p[e] = expf(s[e] - m); sum += p[e]; }
  float inv = 1.f / sum;
#pragma unroll
  for (int e = 0; e < 8; ++e) p[e] *= inv;

  f32x4 o0 = {p[0], p[1], p[2], p[3]};
  f32x4 o1 = {p[4], p[5], p[6], p[7]};
  *(f32x4*)&gprob[(size_t)tok * 8] = o0;
  *(f32x4*)&gprob[(size_t)tok * 8 + 4] = o1;

  int e1 = 0; float p1 = p[0];
#pragma unroll
  for (int e = 1; e < 8; ++e) if (p[e] > p1) { p1 = p[e]; e1 = e; }
  int e2 = -1; float p2 = -1.f;
#pragma unroll
  for (int e = 0; e < 8; ++e) if (e != e1 && p[e] > p2) { p2 = p[e]; e2 = e; }
  float rinv = 1.f / (p1 + p2);

  int pos1 = atomicAdd(&lcnt[e1], 1);
  int pos2 = atomicAdd(&lcnt[e2], 1);
  se1[tid] = e1; sp1[tid] = pos1; sw1[tid] = p1 * rinv;
  se2[tid] = e2; sp2[tid] = pos2; sw2[tid] = p2 * rinv;
  __syncthreads();

  if (tid < 8) sbase[tid] = atomicAdd(&cnt[tid * 32], lcnt[tid]);
  __syncthreads();

  int a1i = sbase[se1[tid]] + sp1[tid];
  lists[se1[tid] * NTOK + a1i] = tok; wts[se1[tid] * NTOK + a1i] = sw1[tid];   // rank0: +w
  int a2i = sbase[se2[tid]] + sp2[tid];
  lists[se2[tid] * NTOK + a2i] = tok; wts[se2[tid] * NTOK + a2i] = -sw2[tid];  // rank1: -w
}

// ---------------- expert layer 1 GEMM (fp16, 512 threads, 128x256 tile) ----------------
// 8 waves (2x4), acc[4][4] each. A gathered once per row-tile (was 2x). XCD-aware decode.
__global__ __launch_bounds__(512) void k_ffn1(const unsigned short* __restrict__ xf16,
                                              const unsigned short* __restrict__ w1t,
                                              const float* __restrict__ b1,
                                              const int* __restrict__ cnt,
                                              const int* __restrict__ lists,
                                              unsigned short* __restrict__ h) {
  int id = blockIdx.x;
  int xcd = id & 7, local = id >> 3;
  int xh = local & 31, e = local >> 5;
  int row0 = ((xh << 3) | xcd) * 128;

  int c = cnt[e * 32];
  if (row0 >= c) return;
  int pfx = 0;
#pragma unroll
  for (int j = 0; j < 8; ++j) if (j < e) pfx += cnt[j * 32];

  __shared__ __align__(16) unsigned short smem[(1024 + 2048) * 8];  // A 16KB | B 32KB; repack union 36.8KB
  __shared__ int stok[128];

  int tid = threadIdx.x;
  int lane = tid & 63;
  int wid = tid >> 6;                 // 0..7
  int wm = wid >> 2, wn = wid & 3;    // wave tile: 64 rows x 64 cols of 128x256
  int ar = lane & 15, kg = lane >> 4;

  if (tid < 128) stok[tid] = lists[e * NTOK + min(row0 + tid, c - 1)];
  __syncthreads();

  const unsigned short* asrc[2];
  unsigned short* ldsA[2];
#pragma unroll
  for (int q = 0; q < 2; ++q) {
    int cb0 = q * 512 + wid * 64;     // wave-uniform chunk base (A: 1024 chunks)
    int ci = cb0 + lane;
    int row = ci >> 3;
    int cb = (ci & 7) ^ (row & 7);
    asrc[q] = xf16 + (size_t)stok[row] * DIM + cb * 8;
    ldsA[q] = &smem[cb0 * 8];
  }
  const unsigned short* bsrc[4];
  unsigned short* ldsB[4];
#pragma unroll
  for (int q = 0; q < 4; ++q) {
    int cb0 = q * 512 + wid * 64;     // B: 2048 chunks (256 rows x 8 chunks)
    int ci = cb0 + lane;
    int row = ci >> 3;                // 0..255 = h-col
    int cb = (ci & 7) ^ (row & 7);
    bsrc[q] = w1t + ((size_t)e * HID + row) * DIM + cb * 8;
    ldsB[q] = &smem[8192 + cb0 * 8];
  }

  f32x4 acc[4][4] = {};

  for (int kt = 0; kt < DIM / 64; ++kt) {
#pragma unroll
    for (int q = 0; q < 2; ++q) gload_lds16(asrc[q] + kt * 64, ldsA[q]);
#pragma unroll
    for (int q = 0; q < 4; ++q) gload_lds16(bsrc[q] + kt * 64, ldsB[q]);
    __syncthreads();
#pragma unroll
    for (int ks = 0; ks < 2; ++ks) {
      int kc = ks * 4 + kg;
      s16x8 a[4], b[4];
#pragma unroll
      for (int m = 0; m < 4; ++m) {
        int row = wm * 64 + m * 16 + ar;
        a[m] = *(const s16x8*)&smem[row * 64 + ((kc ^ (row & 7)) * 8)];
      }
#pragma unroll
      for (int n = 0; n < 4; ++n) {
        int row = wn * 64 + n * 16 + ar;
        b[n] = *(const s16x8*)&smem[8192 + row * 64 + ((kc ^ (row & 7)) * 8)];
      }
#pragma unroll
      for (int m = 0; m < 4; ++m)
#pragma unroll
        for (int n = 0; n < 4; ++n)
          acc[m][n] = __builtin_amdgcn_mfma_f32_16x16x32_f16(a[m], b[n], acc[m][n], 0, 0, 0);
    }
    __syncthreads();
  }

  // epilogue: two 128-col halves through the 128xPADC repack tile
  int hbase = pfx + row0;
#pragma unroll 1
  for (int half = 0; half < 2; ++half) {
    if ((wn >> 1) == half) {
#pragma unroll
      for (int n = 0; n < 4; ++n) {
        int col = (wn & 1) * 64 + n * 16 + ar;   // 0..127 within half
        float bb = b1[e * HID + half * 128 + col];
#pragma unroll
        for (int m = 0; m < 4; ++m) {
          int rloc = wm * 64 + m * 16 + kg * 4;
#pragma unroll
          for (int r = 0; r < 4; ++r)
            smem[(rloc + r) * PADC + col] = f2h(fmaxf(acc[m][n][r] + bb, 0.f));
        }
      }
    }
    __syncthreads();
#pragma unroll
    for (int q = 0; q < 4; ++q) {
      int ci = tid + q * 512;
      int row = ci >> 4, ch = ci & 15;
      if (row0 + row < c) {
        int4 v = *(const int4*)&smem[row * PADC + ch * 8];
        *(int4*)&h[(size_t)(hbase + row) * HID + half * 128 + ch * 8] = v;
      }
    }
    __syncthreads();
  }
}

// ---------------- expert layer 2 GEMM (fp16, 512 threads, 128x256 tile, 3 panels) ----------------
template <bool STORE_PART>
__global__ __launch_bounds__(512) void k_ffn2(const unsigned short* __restrict__ h,
                                              const unsigned short* __restrict__ w2t,
                                              const float* __restrict__ b2,
                                              const int* __restrict__ cnt,
                                              const int* __restrict__ lists,
                                              const float* __restrict__ wts,
                                              unsigned short* __restrict__ part0,
                                              unsigned short* __restrict__ part1,
                                              float* __restrict__ out) {
  int id = blockIdx.x;
  int xcd = id & 7, local = id >> 3;
  int bny = local % 3;
  int r2 = local / 3;
  int xh = r2 & 31, e = r2 >> 5;
  int row0 = ((xh << 3) | xcd) * 128;
  int bn = bny * 256;

  int c = cnt[e * 32];
  if (row0 >= c) return;
  int pfx = 0;
#pragma unroll
  for (int j = 0; j < 8; ++j) if (j < e) pfx += cnt[j * 32];

  __shared__ __align__(16) unsigned short smem[(1024 + 2048) * 8];  // A 16KB | B 32KB; repack union
  __shared__ int stok[128];
  __shared__ float swt[128];

  int tid = threadIdx.x;
  int lane = tid & 63;
  int wid = tid >> 6;
  int wm = wid >> 2, wn = wid & 3;
  int ar = lane & 15, kg = lane >> 4;

  if (tid < 128) {
    int r = row0 + tid;
    stok[tid] = (r < c) ? lists[e * NTOK + r] : 0;
    swt[tid]  = (r < c) ? wts[e * NTOK + r] : 0.f;
  }
  __syncthreads();

  const unsigned short* asrc[2];
  unsigned short* ldsA[2];
#pragma unroll
  for (int q = 0; q < 2; ++q) {
    int cb0 = q * 512 + wid * 64;
    int ci = cb0 + lane;
    int row = ci >> 3;
    int cb = (ci & 7) ^ (row & 7);
    asrc[q] = h + (size_t)(pfx + row0 + row) * HID + cb * 8;
    ldsA[q] = &smem[cb0 * 8];
  }
  const unsigned short* bsrc[4];
  unsigned short* ldsB[4];
#pragma unroll
  for (int q = 0; q < 4; ++q) {
    int cb0 = q * 512 + wid * 64;
    int ci = cb0 + lane;
    int row = ci >> 3;                // 0..255 = out-col within panel
    int cb = (ci & 7) ^ (row & 7);
    bsrc[q] = w2t + ((size_t)e * DIM + bn + row) * HID + cb * 8;
    ldsB[q] = &smem[8192 + cb0 * 8];
  }

  f32x4 acc[4][4] = {};

  for (int kt = 0; kt < HID / 64; ++kt) {
#pragma unroll
    for (int q = 0; q < 2; ++q) gload_lds16(asrc[q] + kt * 64, ldsA[q]);
#pragma unroll
    for (int q = 0; q < 4; ++q) gload_lds16(bsrc[q] + kt * 64, ldsB[q]);
    __syncthreads();
#pragma unroll
    for (int ks = 0; ks < 2; ++ks) {
      int kc = ks * 4 + kg;
      s16x8 a[4], b[4];
#pragma unroll
      for (int m = 0; m < 4; ++m) {
        int row = wm * 64 + m * 16 + ar;
        a[m] = *(const s16x8*)&smem[row * 64 + ((kc ^ (row & 7)) * 8)];
      }
#pragma unroll
      for (int n = 0; n < 4; ++n) {
        int row = wn * 64 + n * 16 + ar;
        b[n] = *(const s16x8*)&smem[8192 + row * 64 + ((kc ^ (row & 7)) * 8)];
      }
#pragma unroll
      for (int m = 0; m < 4; ++m)
#pragma unroll
        for (int n = 0; n < 4; ++n)
          acc[m][n] = __builtin_amdgcn_mfma_f32_16x16x32_f16(a[m], b[n], acc[m][n], 0, 0, 0);
    }
    __syncthreads();
  }

  if constexpr (STORE_PART) {
    // two 128-col halves: weighted bias -> repack tile -> coalesced 16B rank-split stores
#pragma unroll 1
    for (int half = 0; half < 2; ++half) {
      if ((wn >> 1) == half) {
#pragma unroll
        for (int n = 0; n < 4; ++n) {
          int col = (wn & 1) * 64 + n * 16 + ar;  // 0..127 within half
          float bb = b2[e * DIM + bn + half * 128 + col];
#pragma unroll
          for (int m = 0; m < 4; ++m) {
            int rloc = wm * 64 + m * 16 + kg * 4;
#pragma unroll
            for (int r = 0; r < 4; ++r) {
              float w = swt[rloc + r];
              smem[(rloc + r) * PADC + col] = f2bf((acc[m][n][r] + bb) * fabsf(w));
            }
          }
        }
      }
      __syncthreads();
#pragma unroll
      for (int q = 0; q < 4; ++q) {
        int ci = tid + q * 512;
        int row = ci >> 4, ch = ci & 15;
        float w = swt[row];
        if (w != 0.f) {
          unsigned short* dst = (w > 0.f) ? part0 : part1;
          int4 v = *(const int4*)&smem[row * PADC + ch * 8];
          *(int4*)&dst[(size_t)stok[row] * DIM + bn + half * 128 + ch * 8] = v;
        }
      }
      __syncthreads();
    }
  } else {
    // atomic fallback
#pragma unroll
    for (int n = 0; n < 4; ++n) {
      int col = bn + wn * 64 + n * 16 + ar;
      float bb = b2[e * DIM + col];
#pragma unroll
      for (int m = 0; m < 4; ++m) {
        int rloc = wm * 64 + m * 16 + kg * 4;
#pragma unroll
        for (int r = 0; r < 4; ++r) {
          float w = swt[rloc + r];
          if (w != 0.f) {
            float v = (acc[m][n][r] + bb) * fabsf(w);
            atomicAdd(&out[(size_t)stok[rloc + r] * DIM + col], v);
          }
        }
      }
    }
  }
}

// ---------------- combine: out = part0 + part1 (streaming) ----------------
__global__ __launch_bounds__(256) void k_combine(const unsigned short* __restrict__ p0,
                                                 const unsigned short* __restrict__ p1,
                                                 float* __restrict__ out) {
  size_t i = ((size_t)blockIdx.x * 256 + threadIdx.x) * 8;
  int4 a = *(const int4*)(p0 + i);
  int4 b = *(const int4*)(p1 + i);
  unsigned int ua[4] = {(unsigned)a.x, (unsigned)a.y, (unsigned)a.z, (unsigned)a.w};
  unsigned int ub[4] = {(unsigned)b.x, (unsigned)b.y, (unsigned)b.z, (unsigned)b.w};
  float o[8];
#pragma unroll
  for (int q = 0; q < 4; ++q) {
    o[q * 2 + 0] = bf2f(ua[q] & 0xffffu) + bf2f(ub[q] & 0xffffu);
    o[q * 2 + 1] = bf2f(ua[q] >> 16)     + bf2f(ub[q] >> 16);
  }
  *(float4*)(out + i)     = *(float4*)&o[0];
  *(float4*)(out + i + 4) = *(float4*)&o[4];
}

extern "C" void kernel_launch(void* const* d_in, const int* in_sizes, int n_in,
                              void* d_out, int out_size, void* d_ws, size_t ws_size,
                              hipStream_t stream) {
  const float* x   = (const float*)d_in[0];
  const float* W1  = (const float*)d_in[1];
  const float* b1  = (const float*)d_in[2];
  const float* W2  = (const float*)d_in[3];
  const float* b2  = (const float*)d_in[4];
  const float* Wg1 = (const float*)d_in[5];
  const float* bg1 = (const float*)d_in[6];
  const float* Wg2 = (const float*)d_in[7];
  const float* bg2 = (const float*)d_in[8];
  float* out = (float*)d_out;                       // [N][768] then [N][8]
  float* gprob = out + (size_t)NTOK * DIM;

  char* ws = (char*)d_ws;
  size_t off = 0;
  auto alloc = [&](size_t bytes) { void* pp = ws + off; off += (bytes + 255) & ~(size_t)255; return pp; };
  unsigned short* w1t = (unsigned short*)alloc((size_t)NEXP * HID * DIM * 2);
  unsigned short* w2t = (unsigned short*)alloc((size_t)NEXP * DIM * HID * 2);
  float* hgbuf = (float*)alloc((size_t)NTOK * HID * 4);   // hg (fp16, 16MB) U h (fp16, 32MB)
  int* cnt = (int*)alloc(NEXP * 32 * 4);            // 128B-padded counters
  int* lists = (int*)alloc((size_t)NEXP * NTOK * 4);
  float* wts = (float*)alloc((size_t)NEXP * NTOK * 4);
  unsigned short* part0 = (unsigned short*)alloc((size_t)NTOK * DIM * 2);
  unsigned short* part1 = (unsigned short*)alloc((size_t)NTOK * DIM * 2);
  bool store_mode = (off <= ws_size);

  // Gate scratch overlays part0/part1 (written only by k_ffn2/k_combine, which run
  // strictly after every reader of these aliases in stream order). Else: dedicated.
  unsigned short *xf16, *wg1t;
  float* gs; int* rcnt; int* rlist;
  if (store_mode) {
    xf16 = part1;                                    // last read by k_ffn1
    wg1t = part0;                                    // [0, 384KB)
    char* p0b = (char*)part0;
    gs    = (float*)(p0b + (1u << 20));              // [1MB, 2MB)
    rcnt  = (int*)(p0b + 9 * (1u << 18));            // 2.25MB
    rlist = (int*)(p0b + 10 * (1u << 18));           // [2.5MB, +128KB)
  } else {
    xf16  = (unsigned short*)alloc((size_t)NTOK * DIM * 2);
    wg1t  = (unsigned short*)alloc((size_t)DIM * HID * 2);
    gs    = (float*)alloc((size_t)NTOK * 8 * 4);
    rcnt  = (int*)alloc(256);
    rlist = (int*)alloc((size_t)NTOK * 4);
  }

  unsigned short* hg = (unsigned short*)hgbuf;       // fp16 gate hidden (16MB)
  unsigned short* h = (unsigned short*)hgbuf;        // fp16 compact expert hidden (32MB)

  hipMemsetAsync(cnt, 0, NEXP * 32 * sizeof(int), stream);
  hipMemsetAsync(rcnt, 0, sizeof(int), stream);
  if (!store_mode)
    hipMemsetAsync(d_out, 0, (size_t)NTOK * DIM * sizeof(float), stream);

  k_cvt_x<<<(NTOK * DIM) / (256 * 8), 256, 0, stream>>>(x, xf16);
  k_trh<<<dim3(HID / 32, DIM / 32, 1), 256, 0, stream>>>(Wg1, wg1t, DIM, HID);   // -> wg1t[h][d]
  k_trh<<<dim3(HID / 32, DIM / 32, NEXP), 256, 0, stream>>>(W1, w1t, DIM, HID);  // -> w1t[e][h][d]
  k_trh<<<dim3(DIM / 32, HID / 32, NEXP), 256, 0, stream>>>(W2, w2t, HID, DIM);  // -> w2t[e][d][h]
  k_gmfma<<<dim3(NTOK / 128, HID / 128), 256, 0, stream>>>(xf16, wg1t, bg1, hg);
  k_gate2a<<<NTOK / 256, 256, 0, stream>>>(hg, Wg2, bg2, gs, rcnt, rlist);
  k_rescue<<<2048, 256, 0, stream>>>(x, Wg1, bg1, Wg2, bg2, rcnt, rlist, gs);
  k_gate2b<<<NTOK / 256, 256, 0, stream>>>(gs, gprob, cnt, lists, wts);
  k_ffn1<<<(NTOK / 128) * NEXP, 512, 0, stream>>>(xf16, w1t, b1, cnt, lists, h);
  if (store_mode) {
    k_ffn2<true><<<(NTOK / 128) * 3 * NEXP, 512, 0, stream>>>(h, w2t, b2, cnt, lists, wts, part0, part1, out);
    k_combine<<<(NTOK * DIM) / (256 * 8), 256, 0, stream>>>(part0, part1, out);
  } else {
    k_ffn2<false><<<(NTOK / 128) * 3 * NEXP, 512, 0, stream>>>(h, w2t, b2, cnt, lists, wts, part0, part1, out);
  }
}

// Round 18
// 240.735 us; speedup vs baseline: 1.0954x; 1.0954x over previous
//
#include <hip/hip_runtime.h>
#include <hip/hip_bf16.h>
#include <stdint.h>

#define NTOK 32768
#define DIM  768
#define HID  256
#define NEXP 8
#define PADC 144   // repack-tile column pad: conflict-reduced epilogue writes

typedef float f32x4 __attribute__((ext_vector_type(4)));
typedef short s16x8 __attribute__((ext_vector_type(8)));

__device__ __forceinline__ unsigned short f2bf(float f) {
  union { float f; unsigned int u; } c; c.f = f;
  unsigned int r = c.u + 0x7fffu + ((c.u >> 16) & 1u);
  return (unsigned short)(r >> 16);
}

__device__ __forceinline__ float bf2f(unsigned int u) {
  union { unsigned int x; float f; } c; c.x = u << 16; return c.f;
}

__device__ __forceinline__ unsigned short f2h(float f) {
  union { _Float16 h; unsigned short u; } c; c.h = (_Float16)f; return c.u;
}

__device__ __forceinline__ float h2f(unsigned short u) {
  union { unsigned short u; _Float16 h; } c; c.u = u; return (float)c.h;
}

// async global -> LDS, 16B per lane. LDS dest is wave-uniform base + lane*16.
__device__ __forceinline__ void gload_lds16(const unsigned short* g, unsigned short* l) {
  __builtin_amdgcn_global_load_lds((const __attribute__((address_space(1))) void*)g,
                                   (__attribute__((address_space(3))) void*)l, 16, 0, 0);
}

// ---------------- x fp32 -> fp16 (gate + experts) ----------------
__global__ __launch_bounds__(256) void k_cvt_x(const float* __restrict__ x,
                                               unsigned short* __restrict__ xf16) {
  int i = (blockIdx.x * 256 + threadIdx.x) * 8;
  float4 a = *(const float4*)(x + i);
  float4 b = *(const float4*)(x + i + 4);
  float f[8] = {a.x, a.y, a.z, a.w, b.x, b.y, b.z, b.w};
  unsigned short hh[8];
#pragma unroll
  for (int q = 0; q < 8; ++q) hh[q] = f2h(f[q]);
  int4 vh;
  vh.x = (int)((unsigned)hh[0] | ((unsigned)hh[1] << 16));
  vh.y = (int)((unsigned)hh[2] | ((unsigned)hh[3] << 16));
  vh.z = (int)((unsigned)hh[4] | ((unsigned)hh[5] << 16));
  vh.w = (int)((unsigned)hh[6] | ((unsigned)hh[7] << 16));
  *(int4*)(xf16 + i) = vh;
}

// ---------------- fp32 [R][C] -> fp16 [C][R] transpose via LDS tile (per-e slab) ----------------
__global__ __launch_bounds__(256) void k_trh(const float* __restrict__ in,
                                             unsigned short* __restrict__ outp,
                                             int R, int C) {
  __shared__ float tile[32][33];
  int e = blockIdx.z;
  const float* ip = in + (size_t)e * R * C;
  unsigned short* op = outp + (size_t)e * R * C;
  int tx = threadIdx.x & 31, ty = threadIdx.x >> 5;  // 32x8
  int r0 = blockIdx.y * 32, c0 = blockIdx.x * 32;
#pragma unroll
  for (int i = 0; i < 4; ++i)
    tile[ty + i * 8][tx] = ip[(size_t)(r0 + ty + i * 8) * C + c0 + tx];
  __syncthreads();
#pragma unroll
  for (int i = 0; i < 4; ++i)
    op[(size_t)(c0 + ty + i * 8) * R + r0 + tx] = f2h(tile[tx][ty + i * 8]);
}

// ---------------- gate layer 1, fp16 MFMA: hg(fp16) = relu(x @ Wg1 + bg1) ----------------
__global__ __launch_bounds__(256) void k_gmfma(const unsigned short* __restrict__ xh,
                                               const unsigned short* __restrict__ wh,
                                               const float* __restrict__ bg1,
                                               unsigned short* __restrict__ hg) {
  int bm = blockIdx.x * 128;
  int bn = blockIdx.y * 128;

  __shared__ __align__(16) unsigned short Ah[128 * 64];
  __shared__ __align__(16) unsigned short Bh[128 * 64];

  int tid = threadIdx.x;
  int lane = tid & 63;
  int wid = tid >> 6;
  int wm = wid >> 1, wn = wid & 1;
  int ar = lane & 15, kg = lane >> 4;

  const unsigned short *sah[4], *sbh[4];
  unsigned short *dA[4], *dB[4];
#pragma unroll
  for (int i = 0; i < 4; ++i) {
    int cb0 = i * 256 + wid * 64;        // wave-uniform chunk base
    int ci = cb0 + lane;
    int row = ci >> 3;
    int cb = (ci & 7) ^ (row & 7);       // inverse-swizzled source chunk
    sah[i] = xh + (size_t)(bm + row) * DIM + cb * 8;
    sbh[i] = wh + (size_t)(bn + row) * DIM + cb * 8;
    dA[i] = &Ah[cb0 * 8];
    dB[i] = &Bh[cb0 * 8];
  }

  f32x4 acc[4][4] = {};

  for (int kt = 0; kt < DIM / 64; ++kt) {
#pragma unroll
    for (int i = 0; i < 4; ++i) {
      gload_lds16(sah[i] + kt * 64, dA[i]);
      gload_lds16(sbh[i] + kt * 64, dB[i]);
    }
    __syncthreads();
#pragma unroll
    for (int ks = 0; ks < 2; ++ks) {
      int kc = ks * 4 + kg;
      s16x8 a[4], b[4];
#pragma unroll
      for (int m = 0; m < 4; ++m) {
        int row = wm * 64 + m * 16 + ar;
        a[m] = *(const s16x8*)&Ah[row * 64 + ((kc ^ (row & 7)) * 8)];
      }
#pragma unroll
      for (int n = 0; n < 4; ++n) {
        int row = wn * 64 + n * 16 + ar;
        b[n] = *(const s16x8*)&Bh[row * 64 + ((kc ^ (row & 7)) * 8)];
      }
#pragma unroll
      for (int m = 0; m < 4; ++m)
#pragma unroll
        for (int n = 0; n < 4; ++n)
          acc[m][n] = __builtin_amdgcn_mfma_f32_16x16x32_f16(a[m], b[n], acc[m][n], 0, 0, 0);
    }
    __syncthreads();
  }

  // bias + relu -> hg fp16
#pragma unroll
  for (int n = 0; n < 4; ++n) {
    int col = bn + wn * 64 + n * 16 + ar;
    float bb = bg1[col];
#pragma unroll
    for (int m = 0; m < 4; ++m) {
      int rbase = bm + wm * 64 + m * 16 + kg * 4;
#pragma unroll
      for (int r = 0; r < 4; ++r)
        hg[(size_t)(rbase + r) * HID + col] = f2h(fmaxf(acc[m][n][r] + bb, 0.f));
    }
  }
}

// ---------------- gate 2a: scores from hg(fp16) -> gs; flag near-ties for fp32 rescue ----------------
__global__ __launch_bounds__(256) void k_gate2a(const unsigned short* __restrict__ hg,
                                                const float* __restrict__ wg2,
                                                const float* __restrict__ bg2,
                                                float* __restrict__ gs,
                                                int* __restrict__ rcnt,
                                                int* __restrict__ rlist) {
  int tok = blockIdx.x * 256 + threadIdx.x;
  const unsigned short* hrow = hg + (size_t)tok * HID;

  float s[8];
#pragma unroll
  for (int e = 0; e < 8; ++e) s[e] = bg2[e];
#pragma unroll 4
  for (int j = 0; j < 32; ++j) {
    s16x8 hv8 = *(const s16x8*)(hrow + j * 8);
#pragma unroll
    for (int i = 0; i < 8; ++i) {
      float hv = h2f((unsigned short)hv8[i]);
      const float* wr = wg2 + (j * 8 + i) * 8;
#pragma unroll
      for (int e = 0; e < 8; ++e) s[e] += hv * wr[e];
    }
  }

  f32x4 o0 = {s[0], s[1], s[2], s[3]};
  f32x4 o1 = {s[4], s[5], s[6], s[7]};
  *(f32x4*)&gs[(size_t)tok * 8] = o0;
  *(f32x4*)&gs[(size_t)tok * 8 + 4] = o1;

  // top-3 scan; fp16-gate score-gap error sigma ~1e-4. 1e-3 threshold = 10 sigma.
  float m1 = -3e38f, m2 = -3e38f, m3 = -3e38f;
#pragma unroll
  for (int e = 0; e < 8; ++e) {
    float v = s[e];
    if (v > m1)      { m3 = m2; m2 = m1; m1 = v; }
    else if (v > m2) { m3 = m2; m2 = v; }
    else if (v > m3) { m3 = v; }
  }
  if (m2 - m3 < 1e-3f) {
    int i = atomicAdd(rcnt, 1);
    rlist[i] = tok;
  }
}

// ---------------- rescue: exact fp32 gate recompute for flagged tokens ----------------
__global__ __launch_bounds__(256) void k_rescue(const float* __restrict__ x,
                                                const float* __restrict__ wg1,
                                                const float* __restrict__ bg1,
                                                const float* __restrict__ wg2,
                                                const float* __restrict__ bg2,
                                                const int* __restrict__ rcnt,
                                                const int* __restrict__ rlist,
                                                float* __restrict__ gs) {
  __shared__ float xs[DIM];
  __shared__ float ps[4][8];
  int n = rcnt[0];
  int tid = threadIdx.x;
  int lane = tid & 63, wid = tid >> 6;
  for (int idx = blockIdx.x; idx < n; idx += 2048) {
    int tok = rlist[idx];
    __syncthreads();  // protect xs/ps reuse across iterations
#pragma unroll
    for (int q = 0; q < 3; ++q) xs[tid + q * 256] = x[(size_t)tok * DIM + tid + q * 256];
    __syncthreads();
    const float* wcol = wg1 + tid;               // tid = hidden unit (HID==256)
    float pa[8] = {};
#pragma unroll 4
    for (int k0 = 0; k0 < DIM; k0 += 8) {
#pragma unroll
      for (int q = 0; q < 8; ++q)
        pa[q] = fmaf(xs[k0 + q], wcol[(size_t)(k0 + q) * HID], pa[q]);
    }
    float acc = bg1[tid] +
                (((pa[0] + pa[1]) + (pa[2] + pa[3])) + ((pa[4] + pa[5]) + (pa[6] + pa[7])));
    float hj = fmaxf(acc, 0.f);
    float p[8];
#pragma unroll
    for (int e = 0; e < 8; ++e) p[e] = hj * wg2[tid * 8 + e];
#pragma unroll
    for (int off = 32; off >= 1; off >>= 1) {
#pragma unroll
      for (int e = 0; e < 8; ++e) p[e] += __shfl_xor(p[e], off);
    }
    if (lane == 0) {
#pragma unroll
      for (int e = 0; e < 8; ++e) ps[wid][e] = p[e];
    }
    __syncthreads();
    if (tid < 8)
      gs[(size_t)tok * 8 + tid] = bg2[tid] + ps[0][tid] + ps[1][tid] + ps[2][tid] + ps[3][tid];
  }
}

// ---------------- gate 2b: softmax + top2 + routing lists from gs ----------------
__global__ __launch_bounds__(256) void k_gate2b(const float* __restrict__ gs,
                                                float* __restrict__ gprob,
                                                int* __restrict__ cnt,     // stride 32
                                                int* __restrict__ lists,
                                                float* __restrict__ wts) {
  __shared__ int lcnt[8];
  __shared__ int sbase[8];
  __shared__ int se1[256], se2[256], sp1[256], sp2[256];
  __shared__ float sw1[256], sw2[256];
  int tid = threadIdx.x;
  if (tid < 8) lcnt[tid] = 0;
  __syncthreads();

  int tok = blockIdx.x * 256 + tid;
  f32x4 s0v = *(const f32x4*)&gs[(size_t)tok * 8];
  f32x4 s1v = *(const f32x4*)&gs[(size_t)tok * 8 + 4];
  float s[8] = {s0v[0], s0v[1], s0v[2], s0v[3], s1v[0], s1v[1], s1v[2], s1v[3]};

  float m = s[0];
#pragma unroll
  for (int e = 1; e < 8; ++e) m = fmaxf(m, s[e]);
  float p[8]; float sum = 0.f;
#pragma unroll
  for (int e = 0; e < 8; ++e) { p[e] = expf(s[e] - m); sum += p[e]; }
  float inv = 1.f / sum;
#pragma unroll
  for (int e = 0; e < 8; ++e) p[e] *= inv;

  f32x4 o0 = {p[0], p[1], p[2], p[3]};
  f32x4 o1 = {p[4], p[5], p[6], p[7]};
  *(f32x4*)&gprob[(size_t)tok * 8] = o0;
  *(f32x4*)&gprob[(size_t)tok * 8 + 4] = o1;

  int e1 = 0; float p1 = p[0];
#pragma unroll
  for (int e = 1; e < 8; ++e) if (p[e] > p1) { p1 = p[e]; e1 = e; }
  int e2 = -1; float p2 = -1.f;
#pragma unroll
  for (int e = 0; e < 8; ++e) if (e != e1 && p[e] > p2) { p2 = p[e]; e2 = e; }
  float rinv = 1.f / (p1 + p2);

  int pos1 = atomicAdd(&lcnt[e1], 1);
  int pos2 = atomicAdd(&lcnt[e2], 1);
  se1[tid] = e1; sp1[tid] = pos1; sw1[tid] = p1 * rinv;
  se2[tid] = e2; sp2[tid] = pos2; sw2[tid] = p2 * rinv;
  __syncthreads();

  if (tid < 8) sbase[tid] = atomicAdd(&cnt[tid * 32], lcnt[tid]);
  __syncthreads();

  int a1i = sbase[se1[tid]] + sp1[tid];
  lists[se1[tid] * NTOK + a1i] = tok; wts[se1[tid] * NTOK + a1i] = sw1[tid];   // rank0: +w
  int a2i = sbase[se2[tid]] + sp2[tid];
  lists[se2[tid] * NTOK + a2i] = tok; wts[se2[tid] * NTOK + a2i] = -sw2[tid];  // rank1: -w
}

// ---------------- expert layer 1 GEMM (fp16, 512 threads, 128x256 tile) ----------------
// 8 waves (2x4), acc[4][4] each. A gathered once per row-tile. 12 K-steps amortize
// 8-wave barriers (this tile REGRESSES ffn2, which has only 4 K-steps). XCD decode.
__global__ __launch_bounds__(512) void k_ffn1(const unsigned short* __restrict__ xf16,
                                              const unsigned short* __restrict__ w1t,
                                              const float* __restrict__ b1,
                                              const int* __restrict__ cnt,
                                              const int* __restrict__ lists,
                                              unsigned short* __restrict__ h) {
  int id = blockIdx.x;
  int xcd = id & 7, local = id >> 3;
  int xh = local & 31, e = local >> 5;
  int row0 = ((xh << 3) | xcd) * 128;

  int c = cnt[e * 32];
  if (row0 >= c) return;
  int pfx = 0;
#pragma unroll
  for (int j = 0; j < 8; ++j) if (j < e) pfx += cnt[j * 32];

  __shared__ __align__(16) unsigned short smem[(1024 + 2048) * 8];  // A 16KB | B 32KB; repack union
  __shared__ int stok[128];

  int tid = threadIdx.x;
  int lane = tid & 63;
  int wid = tid >> 6;                 // 0..7
  int wm = wid >> 2, wn = wid & 3;    // wave tile: 64 rows x 64 cols of 128x256
  int ar = lane & 15, kg = lane >> 4;

  if (tid < 128) stok[tid] = lists[e * NTOK + min(row0 + tid, c - 1)];
  __syncthreads();

  const unsigned short* asrc[2];
  unsigned short* ldsA[2];
#pragma unroll
  for (int q = 0; q < 2; ++q) {
    int cb0 = q * 512 + wid * 64;     // wave-uniform chunk base (A: 1024 chunks)
    int ci = cb0 + lane;
    int row = ci >> 3;
    int cb = (ci & 7) ^ (row & 7);
    asrc[q] = xf16 + (size_t)stok[row] * DIM + cb * 8;
    ldsA[q] = &smem[cb0 * 8];
  }
  const unsigned short* bsrc[4];
  unsigned short* ldsB[4];
#pragma unroll
  for (int q = 0; q < 4; ++q) {
    int cb0 = q * 512 + wid * 64;     // B: 2048 chunks (256 rows x 8 chunks)
    int ci = cb0 + lane;
    int row = ci >> 3;                // 0..255 = h-col
    int cb = (ci & 7) ^ (row & 7);
    bsrc[q] = w1t + ((size_t)e * HID + row) * DIM + cb * 8;
    ldsB[q] = &smem[8192 + cb0 * 8];
  }

  f32x4 acc[4][4] = {};

  for (int kt = 0; kt < DIM / 64; ++kt) {
#pragma unroll
    for (int q = 0; q < 2; ++q) gload_lds16(asrc[q] + kt * 64, ldsA[q]);
#pragma unroll
    for (int q = 0; q < 4; ++q) gload_lds16(bsrc[q] + kt * 64, ldsB[q]);
    __syncthreads();
#pragma unroll
    for (int ks = 0; ks < 2; ++ks) {
      int kc = ks * 4 + kg;
      s16x8 a[4], b[4];
#pragma unroll
      for (int m = 0; m < 4; ++m) {
        int row = wm * 64 + m * 16 + ar;
        a[m] = *(const s16x8*)&smem[row * 64 + ((kc ^ (row & 7)) * 8)];
      }
#pragma unroll
      for (int n = 0; n < 4; ++n) {
        int row = wn * 64 + n * 16 + ar;
        b[n] = *(const s16x8*)&smem[8192 + row * 64 + ((kc ^ (row & 7)) * 8)];
      }
#pragma unroll
      for (int m = 0; m < 4; ++m)
#pragma unroll
        for (int n = 0; n < 4; ++n)
          acc[m][n] = __builtin_amdgcn_mfma_f32_16x16x32_f16(a[m], b[n], acc[m][n], 0, 0, 0);
    }
    __syncthreads();
  }

  // epilogue: two 128-col halves through the 128xPADC repack tile
  int hbase = pfx + row0;
#pragma unroll 1
  for (int half = 0; half < 2; ++half) {
    if ((wn >> 1) == half) {
#pragma unroll
      for (int n = 0; n < 4; ++n) {
        int col = (wn & 1) * 64 + n * 16 + ar;   // 0..127 within half
        float bb = b1[e * HID + half * 128 + col];
#pragma unroll
        for (int m = 0; m < 4; ++m) {
          int rloc = wm * 64 + m * 16 + kg * 4;
#pragma unroll
          for (int r = 0; r < 4; ++r)
            smem[(rloc + r) * PADC + col] = f2h(fmaxf(acc[m][n][r] + bb, 0.f));
        }
      }
    }
    __syncthreads();
#pragma unroll
    for (int q = 0; q < 4; ++q) {
      int ci = tid + q * 512;
      int row = ci >> 4, ch = ci & 15;
      if (row0 + row < c) {
        int4 v = *(const int4*)&smem[row * PADC + ch * 8];
        *(int4*)&h[(size_t)(hbase + row) * HID + half * 128 + ch * 8] = v;
      }
    }
    __syncthreads();
  }
}

// ---------------- expert layer 2 GEMM (fp16, 256 threads, 128x128 tile, 6 panels) ----------------
// K=256 -> only 4 K-steps: small 4-wave tile wins here (8-wave regressed, round 17).
template <bool STORE_PART>
__global__ __launch_bounds__(256) void k_ffn2(const unsigned short* __restrict__ h,
                                              const unsigned short* __restrict__ w2t,
                                              const float* __restrict__ b2,
                                              const int* __restrict__ cnt,
                                              const int* __restrict__ lists,
                                              const float* __restrict__ wts,
                                              unsigned short* __restrict__ part0,
                                              unsigned short* __restrict__ part1,
                                              float* __restrict__ out) {
  int id = blockIdx.x;
  int xcd = id & 7, local = id >> 3;
  int bny = local % 6;
  int r2 = local / 6;
  int xh = r2 & 31, e = r2 >> 5;
  int row0 = ((xh << 3) | xcd) * 128;
  int bn = bny * 128;

  int c = cnt[e * 32];
  if (row0 >= c) return;
  int pfx = 0;
#pragma unroll
  for (int j = 0; j < 8; ++j) if (j < e) pfx += cnt[j * 32];

  __shared__ __align__(16) unsigned short smem[128 * PADC];  // staging (32KB) U repack tile (36KB)
  __shared__ int stok[128];
  __shared__ float swt[128];
  unsigned short* As = smem;
  unsigned short* Bs = smem + 128 * 64;

  int tid = threadIdx.x;
  int lane = tid & 63;
  int wid = tid >> 6;
  int wm = wid >> 1, wn = wid & 1;
  int ar = lane & 15, kg = lane >> 4;

  if (tid < 128) {
    int r = row0 + tid;
    stok[tid] = (r < c) ? lists[e * NTOK + r] : 0;
    swt[tid]  = (r < c) ? wts[e * NTOK + r] : 0.f;
  }
  __syncthreads();

  const unsigned short* asrc[4];
  const unsigned short* bsrc[4];
  unsigned short* ldsA[4];
  unsigned short* ldsB[4];
#pragma unroll
  for (int i = 0; i < 4; ++i) {
    int cb0 = i * 256 + wid * 64;
    int ci = cb0 + lane;
    int row = ci >> 3;
    int cb = (ci & 7) ^ (row & 7);
    asrc[i] = h + (size_t)(pfx + row0 + row) * HID + cb * 8;
    bsrc[i] = w2t + ((size_t)e * DIM + bn + row) * HID + cb * 8;
    ldsA[i] = &As[cb0 * 8];
    ldsB[i] = &Bs[cb0 * 8];
  }

  f32x4 acc[4][4] = {};

  for (int kt = 0; kt < HID / 64; ++kt) {
#pragma unroll
    for (int i = 0; i < 4; ++i) {
      gload_lds16(asrc[i] + kt * 64, ldsA[i]);
      gload_lds16(bsrc[i] + kt * 64, ldsB[i]);
    }
    __syncthreads();
#pragma unroll
    for (int ks = 0; ks < 2; ++ks) {
      int kc = ks * 4 + kg;
      s16x8 a[4], b[4];
#pragma unroll
      for (int m = 0; m < 4; ++m) {
        int row = wm * 64 + m * 16 + ar;
        a[m] = *(const s16x8*)&As[row * 64 + ((kc ^ (row & 7)) * 8)];
      }
#pragma unroll
      for (int n = 0; n < 4; ++n) {
        int row = wn * 64 + n * 16 + ar;
        b[n] = *(const s16x8*)&Bs[row * 64 + ((kc ^ (row & 7)) * 8)];
      }
#pragma unroll
      for (int m = 0; m < 4; ++m)
#pragma unroll
        for (int n = 0; n < 4; ++n)
          acc[m][n] = __builtin_amdgcn_mfma_f32_16x16x32_f16(a[m], b[n], acc[m][n], 0, 0, 0);
    }
    __syncthreads();
  }

  if constexpr (STORE_PART) {
    // weighted bias epilogue -> LDS repack tile -> coalesced 16B stores per token row
#pragma unroll
    for (int n = 0; n < 4; ++n) {
      int col = wn * 64 + n * 16 + ar;           // within-tile col
      float bb = b2[e * DIM + bn + col];
#pragma unroll
      for (int m = 0; m < 4; ++m) {
        int rloc = wm * 64 + m * 16 + kg * 4;
#pragma unroll
        for (int r = 0; r < 4; ++r) {
          float w = swt[rloc + r];
          smem[(rloc + r) * PADC + col] = f2bf((acc[m][n][r] + bb) * fabsf(w));
        }
      }
    }
    __syncthreads();
#pragma unroll
    for (int q = 0; q < 8; ++q) {
      int ci = tid + q * 256;
      int row = ci >> 4, ch = ci & 15;
      float w = swt[row];
      if (w != 0.f) {
        unsigned short* dst = (w > 0.f) ? part0 : part1;
        int4 v = *(const int4*)&smem[row * PADC + ch * 8];
        *(int4*)&dst[(size_t)stok[row] * DIM + bn + ch * 8] = v;
      }
    }
  } else {
    // atomic fallback
#pragma unroll
    for (int n = 0; n < 4; ++n) {
      int col = bn + wn * 64 + n * 16 + ar;
      float bb = b2[e * DIM + col];
#pragma unroll
      for (int m = 0; m < 4; ++m) {
        int rloc = wm * 64 + m * 16 + kg * 4;
#pragma unroll
        for (int r = 0; r < 4; ++r) {
          float w = swt[rloc + r];
          if (w != 0.f) {
            float v = (acc[m][n][r] + bb) * fabsf(w);
            atomicAdd(&out[(size_t)stok[rloc + r] * DIM + col], v);
          }
        }
      }
    }
  }
}

// ---------------- combine: out = part0 + part1 (streaming) ----------------
__global__ __launch_bounds__(256) void k_combine(const unsigned short* __restrict__ p0,
                                                 const unsigned short* __restrict__ p1,
                                                 float* __restrict__ out) {
  size_t i = ((size_t)blockIdx.x * 256 + threadIdx.x) * 8;
  int4 a = *(const int4*)(p0 + i);
  int4 b = *(const int4*)(p1 + i);
  unsigned int ua[4] = {(unsigned)a.x, (unsigned)a.y, (unsigned)a.z, (unsigned)a.w};
  unsigned int ub[4] = {(unsigned)b.x, (unsigned)b.y, (unsigned)b.z, (unsigned)b.w};
  float o[8];
#pragma unroll
  for (int q = 0; q < 4; ++q) {
    o[q * 2 + 0] = bf2f(ua[q] & 0xffffu) + bf2f(ub[q] & 0xffffu);
    o[q * 2 + 1] = bf2f(ua[q] >> 16)     + bf2f(ub[q] >> 16);
  }
  *(float4*)(out + i)     = *(float4*)&o[0];
  *(float4*)(out + i + 4) = *(float4*)&o[4];
}

extern "C" void kernel_launch(void* const* d_in, const int* in_sizes, int n_in,
                              void* d_out, int out_size, void* d_ws, size_t ws_size,
                              hipStream_t stream) {
  const float* x   = (const float*)d_in[0];
  const float* W1  = (const float*)d_in[1];
  const float* b1  = (const float*)d_in[2];
  const float* W2  = (const float*)d_in[3];
  const float* b2  = (const float*)d_in[4];
  const float* Wg1 = (const float*)d_in[5];
  const float* bg1 = (const float*)d_in[6];
  const float* Wg2 = (const float*)d_in[7];
  const float* bg2 = (const float*)d_in[8];
  float* out = (float*)d_out;                       // [N][768] then [N][8]
  float* gprob = out + (size_t)NTOK * DIM;

  char* ws = (char*)d_ws;
  size_t off = 0;
  auto alloc = [&](size_t bytes) { void* pp = ws + off; off += (bytes + 255) & ~(size_t)255; return pp; };
  unsigned short* w1t = (unsigned short*)alloc((size_t)NEXP * HID * DIM * 2);
  unsigned short* w2t = (unsigned short*)alloc((size_t)NEXP * DIM * HID * 2);
  float* hgbuf = (float*)alloc((size_t)NTOK * HID * 4);   // hg (fp16, 16MB) U h (fp16, 32MB)
  int* cnt = (int*)alloc(NEXP * 32 * 4);            // 128B-padded counters
  int* lists = (int*)alloc((size_t)NEXP * NTOK * 4);
  float* wts = (float*)alloc((size_t)NEXP * NTOK * 4);
  unsigned short* part0 = (unsigned short*)alloc((size_t)NTOK * DIM * 2);
  unsigned short* part1 = (unsigned short*)alloc((size_t)NTOK * DIM * 2);
  bool store_mode = (off <= ws_size);

  // Gate scratch overlays part0/part1 (written only by k_ffn2/k_combine, which run
  // strictly after every reader of these aliases in stream order). Else: dedicated.
  unsigned short *xf16, *wg1t;
  float* gs; int* rcnt; int* rlist;
  if (store_mode) {
    xf16 = part1;                                    // last read by k_ffn1
    wg1t = part0;                                    // [0, 384KB)
    char* p0b = (char*)part0;
    gs    = (float*)(p0b + (1u << 20));              // [1MB, 2MB)
    rcnt  = (int*)(p0b + 9 * (1u << 18));            // 2.25MB
    rlist = (int*)(p0b + 10 * (1u << 18));           // [2.5MB, +128KB)
  } else {
    xf16  = (unsigned short*)alloc((size_t)NTOK * DIM * 2);
    wg1t  = (unsigned short*)alloc((size_t)DIM * HID * 2);
    gs    = (float*)alloc((size_t)NTOK * 8 * 4);
    rcnt  = (int*)alloc(256);
    rlist = (int*)alloc((size_t)NTOK * 4);
  }

  unsigned short* hg = (unsigned short*)hgbuf;       // fp16 gate hidden (16MB)
  unsigned short* h = (unsigned short*)hgbuf;        // fp16 compact expert hidden (32MB)

  hipMemsetAsync(cnt, 0, NEXP * 32 * sizeof(int), stream);
  hipMemsetAsync(rcnt, 0, sizeof(int), stream);
  if (!store_mode)
    hipMemsetAsync(d_out, 0, (size_t)NTOK * DIM * sizeof(float), stream);

  k_cvt_x<<<(NTOK * DIM) / (256 * 8), 256, 0, stream>>>(x, xf16);
  k_trh<<<dim3(HID / 32, DIM / 32, 1), 256, 0, stream>>>(Wg1, wg1t, DIM, HID);   // -> wg1t[h][d]
  k_trh<<<dim3(HID / 32, DIM / 32, NEXP), 256, 0, stream>>>(W1, w1t, DIM, HID);  // -> w1t[e][h][d]
  k_trh<<<dim3(DIM / 32, HID / 32, NEXP), 256, 0, stream>>>(W2, w2t, HID, DIM);  // -> w2t[e][d][h]
  k_gmfma<<<dim3(NTOK / 128, HID / 128), 256, 0, stream>>>(xf16, wg1t, bg1, hg);
  k_gate2a<<<NTOK / 256, 256, 0, stream>>>(hg, Wg2, bg2, gs, rcnt, rlist);
  k_rescue<<<2048, 256, 0, stream>>>(x, Wg1, bg1, Wg2, bg2, rcnt, rlist, gs);
  k_gate2b<<<NTOK / 256, 256, 0, stream>>>(gs, gprob, cnt, lists, wts);
  k_ffn1<<<(NTOK / 128) * NEXP, 512, 0, stream>>>(xf16, w1t, b1, cnt, lists, h);
  if (store_mode) {
    k_ffn2<true><<<(NTOK / 128) * 6 * NEXP, 256, 0, stream>>>(h, w2t, b2, cnt, lists, wts, part0, part1, out);
    k_combine<<<(NTOK * DIM) / (256 * 8), 256, 0, stream>>>(part0, part1, out);
  } else {
    k_ffn2<false><<<(NTOK / 128) * 6 * NEXP, 256, 0, stream>>>(h, w2t, b2, cnt, lists, wts, part0, part1, out);
  }
}

// Round 19
// 227.478 us; speedup vs baseline: 1.1593x; 1.0583x over previous
//
#include <hip/hip_runtime.h>
#include <hip/hip_bf16.h>
#include <stdint.h>

#define NTOK 32768
#define DIM  768
#define HID  256
#define NEXP 8
#define PADC 144   // repack-tile column pad (ffn kernels)

typedef float f32x4 __attribute__((ext_vector_type(4)));
typedef short s16x8 __attribute__((ext_vector_type(8)));

__device__ __forceinline__ unsigned short f2bf(float f) {
  union { float f; unsigned int u; } c; c.f = f;
  unsigned int r = c.u + 0x7fffu + ((c.u >> 16) & 1u);
  return (unsigned short)(r >> 16);
}

__device__ __forceinline__ float bf2f(unsigned int u) {
  union { unsigned int x; float f; } c; c.x = u << 16; return c.f;
}

__device__ __forceinline__ unsigned short f2h(float f) {
  union { _Float16 h; unsigned short u; } c; c.h = (_Float16)f; return c.u;
}

__device__ __forceinline__ float h2f(unsigned short u) {
  union { unsigned short u; _Float16 h; } c; c.u = u; return (float)c.h;
}

// async global -> LDS, 16B per lane. LDS dest is wave-uniform base + lane*16.
__device__ __forceinline__ void gload_lds16(const unsigned short* g, unsigned short* l) {
  __builtin_amdgcn_global_load_lds((const __attribute__((address_space(1))) void*)g,
                                   (__attribute__((address_space(3))) void*)l, 16, 0, 0);
}

// ---------------- x fp32 -> fp16 (gate + experts) ----------------
__global__ __launch_bounds__(256) void k_cvt_x(const float* __restrict__ x,
                                               unsigned short* __restrict__ xf16) {
  int i = (blockIdx.x * 256 + threadIdx.x) * 8;
  float4 a = *(const float4*)(x + i);
  float4 b = *(const float4*)(x + i + 4);
  float f[8] = {a.x, a.y, a.z, a.w, b.x, b.y, b.z, b.w};
  unsigned short hh[8];
#pragma unroll
  for (int q = 0; q < 8; ++q) hh[q] = f2h(f[q]);
  int4 vh;
  vh.x = (int)((unsigned)hh[0] | ((unsigned)hh[1] << 16));
  vh.y = (int)((unsigned)hh[2] | ((unsigned)hh[3] << 16));
  vh.z = (int)((unsigned)hh[4] | ((unsigned)hh[5] << 16));
  vh.w = (int)((unsigned)hh[6] | ((unsigned)hh[7] << 16));
  *(int4*)(xf16 + i) = vh;
}

// ---------------- fp32 [R][C] -> fp16 [C][R] transpose (per-e slab) ----------------
__global__ __launch_bounds__(256) void k_trh(const float* __restrict__ in,
                                             unsigned short* __restrict__ outp,
                                             int R, int C) {
  __shared__ float tile[32][33];
  int e = blockIdx.z;
  const float* ip = in + (size_t)e * R * C;
  unsigned short* op = outp + (size_t)e * R * C;
  int tx = threadIdx.x & 31, ty = threadIdx.x >> 5;  // 32x8
  int r0 = blockIdx.y * 32, c0 = blockIdx.x * 32;
#pragma unroll
  for (int i = 0; i < 4; ++i)
    tile[ty + i * 8][tx] = ip[(size_t)(r0 + ty + i * 8) * C + c0 + tx];
  __syncthreads();
#pragma unroll
  for (int i = 0; i < 4; ++i)
    op[(size_t)(c0 + ty + i * 8) * R + r0 + tx] = f2h(tile[tx][ty + i * 8]);
}

// ---------------- W1 (8 slabs) + Wg1 (1 slab) transpose in one launch ----------------
__global__ __launch_bounds__(256) void k_trh9(const float* __restrict__ W1,
                                              const float* __restrict__ Wg1,
                                              unsigned short* __restrict__ w1t,
                                              unsigned short* __restrict__ wg1t) {
  __shared__ float tile[32][33];
  int z = blockIdx.z;
  const float* ip = (z < 8) ? W1 + (size_t)z * DIM * HID : Wg1;
  unsigned short* op = (z < 8) ? w1t + (size_t)z * DIM * HID : wg1t;
  int tx = threadIdx.x & 31, ty = threadIdx.x >> 5;
  int r0 = blockIdx.y * 32, c0 = blockIdx.x * 32;
#pragma unroll
  for (int i = 0; i < 4; ++i)
    tile[ty + i * 8][tx] = ip[(size_t)(r0 + ty + i * 8) * HID + c0 + tx];
  __syncthreads();
#pragma unroll
  for (int i = 0; i < 4; ++i)
    op[(size_t)(c0 + ty + i * 8) * DIM + r0 + tx] = f2h(tile[tx][ty + i * 8]);
}

// ---------------- fused gate: scores + near-tie flags, no hg round-trip ----------------
// ffn1-skeleton 128x256 tile, 512 threads, 12 K-steps. Epilogue: per 128-col half,
// repack relu(h) into transposed hs[col][tok] LDS tile, dot with LDS-cached Wg2
// (thread = 2 tokens x 1 expert), then in-block top-3 scan + rescue flagging.
__global__ __launch_bounds__(512) void k_gate1f(const unsigned short* __restrict__ xf16,
                                                const unsigned short* __restrict__ wg1t,
                                                const float* __restrict__ bg1,
                                                const float* __restrict__ wg2,
                                                const float* __restrict__ bg2,
                                                float* __restrict__ gs,
                                                int* __restrict__ rcnt,
                                                int* __restrict__ rlist) {
  int bm = blockIdx.x * 128;

  __shared__ __align__(16) unsigned short smem[(1024 + 2048) * 8];  // A 16KB | B 32KB (48KB)
  // epilogue overlays: hs[128cols][132] ushorts @0 (33.8KB); sc fp32[128][8] @16896;
  // wg2s fp32[256][8] @20480 (last 8KB).
  unsigned short* hs = smem;
  float* sc = (float*)&smem[16896];
  float* wg2s = (float*)&smem[20480];

  int tid = threadIdx.x;
  int lane = tid & 63;
  int wid = tid >> 6;                 // 0..7
  int wm = wid >> 2, wn = wid & 3;    // wave tile: 64 rows x 64 cols of 128x256
  int ar = lane & 15, kg = lane >> 4;

  const unsigned short* asrc[2];
  unsigned short* ldsA[2];
#pragma unroll
  for (int q = 0; q < 2; ++q) {
    int cb0 = q * 512 + wid * 64;     // A: 1024 chunks (128 rows x 8)
    int ci = cb0 + lane;
    int row = ci >> 3;
    int cb = (ci & 7) ^ (row & 7);
    asrc[q] = xf16 + (size_t)(bm + row) * DIM + cb * 8;
    ldsA[q] = &smem[cb0 * 8];
  }
  const unsigned short* bsrc[4];
  unsigned short* ldsB[4];
#pragma unroll
  for (int q = 0; q < 4; ++q) {
    int cb0 = q * 512 + wid * 64;     // B: 2048 chunks (256 rows x 8)
    int ci = cb0 + lane;
    int row = ci >> 3;                // 0..255 = h-col
    int cb = (ci & 7) ^ (row & 7);
    bsrc[q] = wg1t + (size_t)row * DIM + cb * 8;
    ldsB[q] = &smem[8192 + cb0 * 8];
  }

  f32x4 acc[4][4] = {};

  for (int kt = 0; kt < DIM / 64; ++kt) {
#pragma unroll
    for (int q = 0; q < 2; ++q) gload_lds16(asrc[q] + kt * 64, ldsA[q]);
#pragma unroll
    for (int q = 0; q < 4; ++q) gload_lds16(bsrc[q] + kt * 64, ldsB[q]);
    __syncthreads();
#pragma unroll
    for (int ks = 0; ks < 2; ++ks) {
      int kc = ks * 4 + kg;
      s16x8 a[4], b[4];
#pragma unroll
      for (int m = 0; m < 4; ++m) {
        int row = wm * 64 + m * 16 + ar;
        a[m] = *(const s16x8*)&smem[row * 64 + ((kc ^ (row & 7)) * 8)];
      }
#pragma unroll
      for (int n = 0; n < 4; ++n) {
        int row = wn * 64 + n * 16 + ar;
        b[n] = *(const s16x8*)&smem[8192 + row * 64 + ((kc ^ (row & 7)) * 8)];
      }
#pragma unroll
      for (int m = 0; m < 4; ++m)
#pragma unroll
        for (int n = 0; n < 4; ++n)
          acc[m][n] = __builtin_amdgcn_mfma_f32_16x16x32_f16(a[m], b[n], acc[m][n], 0, 0, 0);
    }
    __syncthreads();
  }

  // stage Wg2 (8KB fp32) into the dead B-staging tail
#pragma unroll
  for (int j = 0; j < 4; ++j) wg2s[tid * 4 + j] = wg2[tid * 4 + j];

  // per-half: repack relu(h) -> hs[col][tok], then accumulate scores
  int tok2 = (tid & 63) * 2;
  int ex = tid >> 6;                   // expert 0..7
  float s0 = 0.f, s1 = 0.f;
#pragma unroll 1
  for (int half = 0; half < 2; ++half) {
    if ((wn >> 1) == half) {
#pragma unroll
      for (int n = 0; n < 4; ++n) {
        int col = (wn & 1) * 64 + n * 16 + ar;   // 0..127 within half
        float bb = bg1[half * 128 + col];
#pragma unroll
        for (int m = 0; m < 4; ++m) {
          int rbase = wm * 64 + m * 16 + kg * 4;
#pragma unroll
          for (int r = 0; r < 4; ++r)
            hs[col * 132 + rbase + r] = f2h(fmaxf(acc[m][n][r] + bb, 0.f));
        }
      }
    }
    __syncthreads();   // hs (and, first pass, wg2s) visible
#pragma unroll 8
    for (int c = 0; c < 128; ++c) {
      unsigned int pair = *(const unsigned int*)&hs[c * 132 + tok2];
      float h0 = h2f((unsigned short)(pair & 0xffffu));
      float h1 = h2f((unsigned short)(pair >> 16));
      float w = wg2s[(half * 128 + c) * 8 + ex];
      s0 = fmaf(h0, w, s0);
      s1 = fmaf(h1, w, s1);
    }
    __syncthreads();   // done reading hs before next half overwrites
  }

  float b2e = bg2[ex];
  s0 += b2e; s1 += b2e;
  gs[(size_t)(bm + tok2) * 8 + ex] = s0;
  gs[(size_t)(bm + tok2 + 1) * 8 + ex] = s1;
  sc[tok2 * 8 + ex] = s0;
  sc[tok2 * 8 + 8 + ex] = s1;
  __syncthreads();

  // top-3 scan per token; fp16-gate score-gap error sigma ~1e-4; 1e-3 = 10 sigma
  if (tid < 128) {
    float m1 = -3e38f, m2 = -3e38f, m3 = -3e38f;
#pragma unroll
    for (int e = 0; e < 8; ++e) {
      float v = sc[tid * 8 + e];
      if (v > m1)      { m3 = m2; m2 = m1; m1 = v; }
      else if (v > m2) { m3 = m2; m2 = v; }
      else if (v > m3) { m3 = v; }
    }
    if (m2 - m3 < 1e-3f) {
      int i = atomicAdd(rcnt, 1);
      rlist[i] = bm + tid;
    }
  }
}

// ---------------- rescue: exact fp32 gate recompute for flagged tokens ----------------
__global__ __launch_bounds__(256) void k_rescue(const float* __restrict__ x,
                                                const float* __restrict__ wg1,
                                                const float* __restrict__ bg1,
                                                const float* __restrict__ wg2,
                                                const float* __restrict__ bg2,
                                                const int* __restrict__ rcnt,
                                                const int* __restrict__ rlist,
                                                float* __restrict__ gs) {
  __shared__ float xs[DIM];
  __shared__ float ps[4][8];
  int n = rcnt[0];
  int tid = threadIdx.x;
  int lane = tid & 63, wid = tid >> 6;
  for (int idx = blockIdx.x; idx < n; idx += 2048) {
    int tok = rlist[idx];
    __syncthreads();  // protect xs/ps reuse across iterations
#pragma unroll
    for (int q = 0; q < 3; ++q) xs[tid + q * 256] = x[(size_t)tok * DIM + tid + q * 256];
    __syncthreads();
    const float* wcol = wg1 + tid;               // tid = hidden unit (HID==256)
    float pa[8] = {};
#pragma unroll 4
    for (int k0 = 0; k0 < DIM; k0 += 8) {
#pragma unroll
      for (int q = 0; q < 8; ++q)
        pa[q] = fmaf(xs[k0 + q], wcol[(size_t)(k0 + q) * HID], pa[q]);
    }
    float acc = bg1[tid] +
                (((pa[0] + pa[1]) + (pa[2] + pa[3])) + ((pa[4] + pa[5]) + (pa[6] + pa[7])));
    float hj = fmaxf(acc, 0.f);
    float p[8];
#pragma unroll
    for (int e = 0; e < 8; ++e) p[e] = hj * wg2[tid * 8 + e];
#pragma unroll
    for (int off = 32; off >= 1; off >>= 1) {
#pragma unroll
      for (int e = 0; e < 8; ++e) p[e] += __shfl_xor(p[e], off);
    }
    if (lane == 0) {
#pragma unroll
      for (int e = 0; e < 8; ++e) ps[wid][e] = p[e];
    }
    __syncthreads();
    if (tid < 8)
      gs[(size_t)tok * 8 + tid] = bg2[tid] + ps[0][tid] + ps[1][tid] + ps[2][tid] + ps[3][tid];
  }
}

// ---------------- gate 2b: softmax + top2 + routing lists from gs ----------------
__global__ __launch_bounds__(256) void k_gate2b(const float* __restrict__ gs,
                                                float* __restrict__ gprob,
                                                int* __restrict__ cnt,     // stride 32
                                                int* __restrict__ lists,
                                                float* __restrict__ wts) {
  __shared__ int lcnt[8];
  __shared__ int sbase[8];
  __shared__ int se1[256], se2[256], sp1[256], sp2[256];
  __shared__ float sw1[256], sw2[256];
  int tid = threadIdx.x;
  if (tid < 8) lcnt[tid] = 0;
  __syncthreads();

  int tok = blockIdx.x * 256 + tid;
  f32x4 s0v = *(const f32x4*)&gs[(size_t)tok * 8];
  f32x4 s1v = *(const f32x4*)&gs[(size_t)tok * 8 + 4];
  float s[8] = {s0v[0], s0v[1], s0v[2], s0v[3], s1v[0], s1v[1], s1v[2], s1v[3]};

  float m = s[0];
#pragma unroll
  for (int e = 1; e < 8; ++e) m = fmaxf(m, s[e]);
  float p[8]; float sum = 0.f;
#pragma unroll
  for (int e = 0; e < 8; ++e) { p[e] = expf(s[e] - m); sum += p[e]; }
  float inv = 1.f / sum;
#pragma unroll
  for (int e = 0; e < 8; ++e) p[e] *= inv;

  f32x4 o0 = {p[0], p[1], p[2], p[3]};
  f32x4 o1 = {p[4], p[5], p[6], p[7]};
  *(f32x4*)&gprob[(size_t)tok * 8] = o0;
  *(f32x4*)&gprob[(size_t)tok * 8 + 4] = o1;

  int e1 = 0; float p1 = p[0];
#pragma unroll
  for (int e = 1; e < 8; ++e) if (p[e] > p1) { p1 = p[e]; e1 = e; }
  int e2 = -1; float p2 = -1.f;
#pragma unroll
  for (int e = 0; e < 8; ++e) if (e != e1 && p[e] > p2) { p2 = p[e]; e2 = e; }
  float rinv = 1.f / (p1 + p2);

  int pos1 = atomicAdd(&lcnt[e1], 1);
  int pos2 = atomicAdd(&lcnt[e2], 1);
  se1[tid] = e1; sp1[tid] = pos1; sw1[tid] = p1 * rinv;
  se2[tid] = e2; sp2[tid] = pos2; sw2[tid] = p2 * rinv;
  __syncthreads();

  if (tid < 8) sbase[tid] = atomicAdd(&cnt[tid * 32], lcnt[tid]);
  __syncthreads();

  int a1i = sbase[se1[tid]] + sp1[tid];
  lists[se1[tid] * NTOK + a1i] = tok; wts[se1[tid] * NTOK + a1i] = sw1[tid];   // rank0: +w
  int a2i = sbase[se2[tid]] + sp2[tid];
  lists[se2[tid] * NTOK + a2i] = tok; wts[se2[tid] * NTOK + a2i] = -sw2[tid];  // rank1: -w
}

// ---------------- expert layer 1 GEMM (fp16, 512 threads, 128x256 tile) ----------------
__global__ __launch_bounds__(512) void k_ffn1(const unsigned short* __restrict__ xf16,
                                              const unsigned short* __restrict__ w1t,
                                              const float* __restrict__ b1,
                                              const int* __restrict__ cnt,
                                              const int* __restrict__ lists,
                                              unsigned short* __restrict__ h) {
  int id = blockIdx.x;
  int xcd = id & 7, local = id >> 3;
  int xh = local & 31, e = local >> 5;
  int row0 = ((xh << 3) | xcd) * 128;

  int c = cnt[e * 32];
  if (row0 >= c) return;
  int pfx = 0;
#pragma unroll
  for (int j = 0; j < 8; ++j) if (j < e) pfx += cnt[j * 32];

  __shared__ __align__(16) unsigned short smem[(1024 + 2048) * 8];  // A 16KB | B 32KB; repack union
  __shared__ int stok[128];

  int tid = threadIdx.x;
  int lane = tid & 63;
  int wid = tid >> 6;
  int wm = wid >> 2, wn = wid & 3;
  int ar = lane & 15, kg = lane >> 4;

  if (tid < 128) stok[tid] = lists[e * NTOK + min(row0 + tid, c - 1)];
  __syncthreads();

  const unsigned short* asrc[2];
  unsigned short* ldsA[2];
#pragma unroll
  for (int q = 0; q < 2; ++q) {
    int cb0 = q * 512 + wid * 64;
    int ci = cb0 + lane;
    int row = ci >> 3;
    int cb = (ci & 7) ^ (row & 7);
    asrc[q] = xf16 + (size_t)stok[row] * DIM + cb * 8;
    ldsA[q] = &smem[cb0 * 8];
  }
  const unsigned short* bsrc[4];
  unsigned short* ldsB[4];
#pragma unroll
  for (int q = 0; q < 4; ++q) {
    int cb0 = q * 512 + wid * 64;
    int ci = cb0 + lane;
    int row = ci >> 3;
    int cb = (ci & 7) ^ (row & 7);
    bsrc[q] = w1t + ((size_t)e * HID + row) * DIM + cb * 8;
    ldsB[q] = &smem[8192 + cb0 * 8];
  }

  f32x4 acc[4][4] = {};

  for (int kt = 0; kt < DIM / 64; ++kt) {
#pragma unroll
    for (int q = 0; q < 2; ++q) gload_lds16(asrc[q] + kt * 64, ldsA[q]);
#pragma unroll
    for (int q = 0; q < 4; ++q) gload_lds16(bsrc[q] + kt * 64, ldsB[q]);
    __syncthreads();
#pragma unroll
    for (int ks = 0; ks < 2; ++ks) {
      int kc = ks * 4 + kg;
      s16x8 a[4], b[4];
#pragma unroll
      for (int m = 0; m < 4; ++m) {
        int row = wm * 64 + m * 16 + ar;
        a[m] = *(const s16x8*)&smem[row * 64 + ((kc ^ (row & 7)) * 8)];
      }
#pragma unroll
      for (int n = 0; n < 4; ++n) {
        int row = wn * 64 + n * 16 + ar;
        b[n] = *(const s16x8*)&smem[8192 + row * 64 + ((kc ^ (row & 7)) * 8)];
      }
#pragma unroll
      for (int m = 0; m < 4; ++m)
#pragma unroll
        for (int n = 0; n < 4; ++n)
          acc[m][n] = __builtin_amdgcn_mfma_f32_16x16x32_f16(a[m], b[n], acc[m][n], 0, 0, 0);
    }
    __syncthreads();
  }

  // epilogue: two 128-col halves through the 128xPADC repack tile
  int hbase = pfx + row0;
#pragma unroll 1
  for (int half = 0; half < 2; ++half) {
    if ((wn >> 1) == half) {
#pragma unroll
      for (int n = 0; n < 4; ++n) {
        int col = (wn & 1) * 64 + n * 16 + ar;
        float bb = b1[e * HID + half * 128 + col];
#pragma unroll
        for (int m = 0; m < 4; ++m) {
          int rloc = wm * 64 + m * 16 + kg * 4;
#pragma unroll
          for (int r = 0; r < 4; ++r)
            smem[(rloc + r) * PADC + col] = f2h(fmaxf(acc[m][n][r] + bb, 0.f));
        }
      }
    }
    __syncthreads();
#pragma unroll
    for (int q = 0; q < 4; ++q) {
      int ci = tid + q * 512;
      int row = ci >> 4, ch = ci & 15;
      if (row0 + row < c) {
        int4 v = *(const int4*)&smem[row * PADC + ch * 8];
        *(int4*)&h[(size_t)(hbase + row) * HID + half * 128 + ch * 8] = v;
      }
    }
    __syncthreads();
  }
}

// ---------------- expert layer 2 GEMM (fp16, 256 threads, 128x128 tile, 6 panels) ----------------
template <bool STORE_PART>
__global__ __launch_bounds__(256) void k_ffn2(const unsigned short* __restrict__ h,
                                              const unsigned short* __restrict__ w2t,
                                              const float* __restrict__ b2,
                                              const int* __restrict__ cnt,
                                              const int* __restrict__ lists,
                                              const float* __restrict__ wts,
                                              unsigned short* __restrict__ part0,
                                              unsigned short* __restrict__ part1,
                                              float* __restrict__ out) {
  int id = blockIdx.x;
  int xcd = id & 7, local = id >> 3;
  int bny = local % 6;
  int r2 = local / 6;
  int xh = r2 & 31, e = r2 >> 5;
  int row0 = ((xh << 3) | xcd) * 128;
  int bn = bny * 128;

  int c = cnt[e * 32];
  if (row0 >= c) return;
  int pfx = 0;
#pragma unroll
  for (int j = 0; j < 8; ++j) if (j < e) pfx += cnt[j * 32];

  __shared__ __align__(16) unsigned short smem[128 * PADC];  // staging (32KB) U repack tile (36KB)
  __shared__ int stok[128];
  __shared__ float swt[128];
  unsigned short* As = smem;
  unsigned short* Bs = smem + 128 * 64;

  int tid = threadIdx.x;
  int lane = tid & 63;
  int wid = tid >> 6;
  int wm = wid >> 1, wn = wid & 1;
  int ar = lane & 15, kg = lane >> 4;

  if (tid < 128) {
    int r = row0 + tid;
    stok[tid] = (r < c) ? lists[e * NTOK + r] : 0;
    swt[tid]  = (r < c) ? wts[e * NTOK + r] : 0.f;
  }
  __syncthreads();

  const unsigned short* asrc[4];
  const unsigned short* bsrc[4];
  unsigned short* ldsA[4];
  unsigned short* ldsB[4];
#pragma unroll
  for (int i = 0; i < 4; ++i) {
    int cb0 = i * 256 + wid * 64;
    int ci = cb0 + lane;
    int row = ci >> 3;
    int cb = (ci & 7) ^ (row & 7);
    asrc[i] = h + (size_t)(pfx + row0 + row) * HID + cb * 8;
    bsrc[i] = w2t + ((size_t)e * DIM + bn + row) * HID + cb * 8;
    ldsA[i] = &As[cb0 * 8];
    ldsB[i] = &Bs[cb0 * 8];
  }

  f32x4 acc[4][4] = {};

  for (int kt = 0; kt < HID / 64; ++kt) {
#pragma unroll
    for (int i = 0; i < 4; ++i) {
      gload_lds16(asrc[i] + kt * 64, ldsA[i]);
      gload_lds16(bsrc[i] + kt * 64, ldsB[i]);
    }
    __syncthreads();
#pragma unroll
    for (int ks = 0; ks < 2; ++ks) {
      int kc = ks * 4 + kg;
      s16x8 a[4], b[4];
#pragma unroll
      for (int m = 0; m < 4; ++m) {
        int row = wm * 64 + m * 16 + ar;
        a[m] = *(const s16x8*)&As[row * 64 + ((kc ^ (row & 7)) * 8)];
      }
#pragma unroll
      for (int n = 0; n < 4; ++n) {
        int row = wn * 64 + n * 16 + ar;
        b[n] = *(const s16x8*)&Bs[row * 64 + ((kc ^ (row & 7)) * 8)];
      }
#pragma unroll
      for (int m = 0; m < 4; ++m)
#pragma unroll
        for (int n = 0; n < 4; ++n)
          acc[m][n] = __builtin_amdgcn_mfma_f32_16x16x32_f16(a[m], b[n], acc[m][n], 0, 0, 0);
    }
    __syncthreads();
  }

  if constexpr (STORE_PART) {
#pragma unroll
    for (int n = 0; n < 4; ++n) {
      int col = wn * 64 + n * 16 + ar;
      float bb = b2[e * DIM + bn + col];
#pragma unroll
      for (int m = 0; m < 4; ++m) {
        int rloc = wm * 64 + m * 16 + kg * 4;
#pragma unroll
        for (int r = 0; r < 4; ++r) {
          float w = swt[rloc + r];
          smem[(rloc + r) * PADC + col] = f2bf((acc[m][n][r] + bb) * fabsf(w));
        }
      }
    }
    __syncthreads();
#pragma unroll
    for (int q = 0; q < 8; ++q) {
      int ci = tid + q * 256;
      int row = ci >> 4, ch = ci & 15;
      float w = swt[row];
      if (w != 0.f) {
        unsigned short* dst = (w > 0.f) ? part0 : part1;
        int4 v = *(const int4*)&smem[row * PADC + ch * 8];
        *(int4*)&dst[(size_t)stok[row] * DIM + bn + ch * 8] = v;
      }
    }
  } else {
#pragma unroll
    for (int n = 0; n < 4; ++n) {
      int col = bn + wn * 64 + n * 16 + ar;
      float bb = b2[e * DIM + col];
#pragma unroll
      for (int m = 0; m < 4; ++m) {
        int rloc = wm * 64 + m * 16 + kg * 4;
#pragma unroll
        for (int r = 0; r < 4; ++r) {
          float w = swt[rloc + r];
          if (w != 0.f) {
            float v = (acc[m][n][r] + bb) * fabsf(w);
            atomicAdd(&out[(size_t)stok[rloc + r] * DIM + col], v);
          }
        }
      }
    }
  }
}

// ---------------- combine: out = part0 + part1 (streaming) ----------------
__global__ __launch_bounds__(256) void k_combine(const unsigned short* __restrict__ p0,
                                                 const unsigned short* __restrict__ p1,
                                                 float* __restrict__ out) {
  size_t i = ((size_t)blockIdx.x * 256 + threadIdx.x) * 8;
  int4 a = *(const int4*)(p0 + i);
  int4 b = *(const int4*)(p1 + i);
  unsigned int ua[4] = {(unsigned)a.x, (unsigned)a.y, (unsigned)a.z, (unsigned)a.w};
  unsigned int ub[4] = {(unsigned)b.x, (unsigned)b.y, (unsigned)b.z, (unsigned)b.w};
  float o[8];
#pragma unroll
  for (int q = 0; q < 4; ++q) {
    o[q * 2 + 0] = bf2f(ua[q] & 0xffffu) + bf2f(ub[q] & 0xffffu);
    o[q * 2 + 1] = bf2f(ua[q] >> 16)     + bf2f(ub[q] >> 16);
  }
  *(float4*)(out + i)     = *(float4*)&o[0];
  *(float4*)(out + i + 4) = *(float4*)&o[4];
}

extern "C" void kernel_launch(void* const* d_in, const int* in_sizes, int n_in,
                              void* d_out, int out_size, void* d_ws, size_t ws_size,
                              hipStream_t stream) {
  const float* x   = (const float*)d_in[0];
  const float* W1  = (const float*)d_in[1];
  const float* b1  = (const float*)d_in[2];
  const float* W2  = (const float*)d_in[3];
  const float* b2  = (const float*)d_in[4];
  const float* Wg1 = (const float*)d_in[5];
  const float* bg1 = (const float*)d_in[6];
  const float* Wg2 = (const float*)d_in[7];
  const float* bg2 = (const float*)d_in[8];
  float* out = (float*)d_out;                       // [N][768] then [N][8]
  float* gprob = out + (size_t)NTOK * DIM;

  char* ws = (char*)d_ws;
  size_t off = 0;
  auto alloc = [&](size_t bytes) { void* pp = ws + off; off += (bytes + 255) & ~(size_t)255; return pp; };
  unsigned short* w1t = (unsigned short*)alloc((size_t)NEXP * HID * DIM * 2);
  unsigned short* w2t = (unsigned short*)alloc((size_t)NEXP * DIM * HID * 2);
  float* hgbuf = (float*)alloc((size_t)NTOK * HID * 4);   // h (fp16, 32MB)
  int* cnt = (int*)alloc(NEXP * 32 * 4);            // 128B-padded counters
  int* lists = (int*)alloc((size_t)NEXP * NTOK * 4);
  float* wts = (float*)alloc((size_t)NEXP * NTOK * 4);
  unsigned short* part0 = (unsigned short*)alloc((size_t)NTOK * DIM * 2);
  unsigned short* part1 = (unsigned short*)alloc((size_t)NTOK * DIM * 2);
  bool store_mode = (off <= ws_size);

  // Gate scratch overlays part0/part1 (written only by k_ffn2/k_combine, which run
  // strictly after every reader of these aliases in stream order). Else: dedicated.
  unsigned short *xf16, *wg1t;
  float* gs; int* rcnt; int* rlist;
  if (store_mode) {
    xf16 = part1;                                    // last read by k_ffn1
    wg1t = part0;                                    // [0, 384KB)
    char* p0b = (char*)part0;
    gs    = (float*)(p0b + (1u << 20));              // [1MB, 2MB)
    rcnt  = (int*)(p0b + 9 * (1u << 18));            // 2.25MB
    rlist = (int*)(p0b + 10 * (1u << 18));           // [2.5MB, +128KB)
  } else {
    xf16  = (unsigned short*)alloc((size_t)NTOK * DIM * 2);
    wg1t  = (unsigned short*)alloc((size_t)DIM * HID * 2);
    gs    = (float*)alloc((size_t)NTOK * 8 * 4);
    rcnt  = (int*)alloc(256);
    rlist = (int*)alloc((size_t)NTOK * 4);
  }

  unsigned short* h = (unsigned short*)hgbuf;        // fp16 compact expert hidden (32MB)

  hipMemsetAsync(cnt, 0, NEXP * 32 * sizeof(int), stream);
  hipMemsetAsync(rcnt, 0, sizeof(int), stream);
  if (!store_mode)
    hipMemsetAsync(d_out, 0, (size_t)NTOK * DIM * sizeof(float), stream);

  k_cvt_x<<<(NTOK * DIM) / (256 * 8), 256, 0, stream>>>(x, xf16);
  k_trh9<<<dim3(HID / 32, DIM / 32, 9), 256, 0, stream>>>(W1, Wg1, w1t, wg1t);   // W1 + Wg1
  k_trh<<<dim3(DIM / 32, HID / 32, NEXP), 256, 0, stream>>>(W2, w2t, HID, DIM);  // -> w2t[e][d][h]
  k_gate1f<<<NTOK / 128, 512, 0, stream>>>(xf16, wg1t, bg1, Wg2, bg2, gs, rcnt, rlist);
  k_rescue<<<2048, 256, 0, stream>>>(x, Wg1, bg1, Wg2, bg2, rcnt, rlist, gs);
  k_gate2b<<<NTOK / 256, 256, 0, stream>>>(gs, gprob, cnt, lists, wts);
  k_ffn1<<<(NTOK / 128) * NEXP, 512, 0, stream>>>(xf16, w1t, b1, cnt, lists, h);
  if (store_mode) {
    k_ffn2<true><<<(NTOK / 128) * 6 * NEXP, 256, 0, stream>>>(h, w2t, b2, cnt, lists, wts, part0, part1, out);
    k_combine<<<(NTOK * DIM) / (256 * 8), 256, 0, stream>>>(part0, part1, out);
  } else {
    k_ffn2<false><<<(NTOK / 128) * 6 * NEXP, 256, 0, stream>>>(h, w2t, b2, cnt, lists, wts, part0, part1, out);
  }
}

// Round 20
// 222.283 us; speedup vs baseline: 1.1864x; 1.0234x over previous
//
#include <hip/hip_runtime.h>
#include <hip/hip_bf16.h>
#include <stdint.h>

#define NTOK 32768
#define DIM  768
#define HID  256
#define NEXP 8
#define PADC 144   // repack-tile column pad (ffn kernels)

typedef float f32x4 __attribute__((ext_vector_type(4)));
typedef short s16x8 __attribute__((ext_vector_type(8)));

__device__ __forceinline__ unsigned short f2bf(float f) {
  union { float f; unsigned int u; } c; c.f = f;
  unsigned int r = c.u + 0x7fffu + ((c.u >> 16) & 1u);
  return (unsigned short)(r >> 16);
}

__device__ __forceinline__ float bf2f(unsigned int u) {
  union { unsigned int x; float f; } c; c.x = u << 16; return c.f;
}

__device__ __forceinline__ unsigned short f2h(float f) {
  union { _Float16 h; unsigned short u; } c; c.h = (_Float16)f; return c.u;
}

__device__ __forceinline__ float h2f(unsigned short u) {
  union { unsigned short u; _Float16 h; } c; c.u = u; return (float)c.h;
}

// async global -> LDS, 16B per lane. LDS dest is wave-uniform base + lane*16.
__device__ __forceinline__ void gload_lds16(const unsigned short* g, unsigned short* l) {
  __builtin_amdgcn_global_load_lds((const __attribute__((address_space(1))) void*)g,
                                   (__attribute__((address_space(3))) void*)l, 16, 0, 0);
}

// ---------------- x fp32 -> fp16 (gate + experts) ----------------
__global__ __launch_bounds__(256) void k_cvt_x(const float* __restrict__ x,
                                               unsigned short* __restrict__ xf16) {
  int i = (blockIdx.x * 256 + threadIdx.x) * 8;
  float4 a = *(const float4*)(x + i);
  float4 b = *(const float4*)(x + i + 4);
  float f[8] = {a.x, a.y, a.z, a.w, b.x, b.y, b.z, b.w};
  unsigned short hh[8];
#pragma unroll
  for (int q = 0; q < 8; ++q) hh[q] = f2h(f[q]);
  int4 vh;
  vh.x = (int)((unsigned)hh[0] | ((unsigned)hh[1] << 16));
  vh.y = (int)((unsigned)hh[2] | ((unsigned)hh[3] << 16));
  vh.z = (int)((unsigned)hh[4] | ((unsigned)hh[5] << 16));
  vh.w = (int)((unsigned)hh[6] | ((unsigned)hh[7] << 16));
  *(int4*)(xf16 + i) = vh;
}

// ---------------- ALL weight transposes in one launch (17 z-slabs) ----------------
// z in [0,7]: W1 slab e=z  (768x256 -> [256][768])
// z == 8   : Wg1           (768x256 -> [256][768])
// z in [9,16]: W2 slab e=z-9 (256x768 -> [768][256])
__global__ __launch_bounds__(256) void k_trall(const float* __restrict__ W1,
                                               const float* __restrict__ Wg1,
                                               const float* __restrict__ W2,
                                               unsigned short* __restrict__ w1t,
                                               unsigned short* __restrict__ wg1t,
                                               unsigned short* __restrict__ w2t) {
  __shared__ float tile[32][33];
  int z = blockIdx.z;
  const float* ip;
  unsigned short* op;
  int R, C;
  if (z < 8)       { ip = W1 + (size_t)z * DIM * HID;  op = w1t + (size_t)z * DIM * HID;  R = DIM; C = HID; }
  else if (z == 8) { ip = Wg1;                          op = wg1t;                          R = DIM; C = HID; }
  else             { ip = W2 + (size_t)(z - 9) * HID * DIM; op = w2t + (size_t)(z - 9) * HID * DIM; R = HID; C = DIM; }
  int r0 = blockIdx.y * 32, c0 = blockIdx.x * 32;
  if (r0 >= R || c0 >= C) return;
  int tx = threadIdx.x & 31, ty = threadIdx.x >> 5;  // 32x8
#pragma unroll
  for (int i = 0; i < 4; ++i)
    tile[ty + i * 8][tx] = ip[(size_t)(r0 + ty + i * 8) * C + c0 + tx];
  __syncthreads();
#pragma unroll
  for (int i = 0; i < 4; ++i)
    op[(size_t)(c0 + ty + i * 8) * R + r0 + tx] = f2h(tile[tx][ty + i * 8]);
}

// ---------------- fused gate: scores + near-tie flags, no hg round-trip ----------------
// ffn1-skeleton 128x256 tile, 512 threads, 12 K-steps. Epilogue: per 128-col half,
// repack relu(h) into transposed hs[col][tok] LDS tile, dot with LDS-cached Wg2
// (thread = 2 tokens x 1 expert), then in-block top-3 scan + rescue flagging.
__global__ __launch_bounds__(512) void k_gate1f(const unsigned short* __restrict__ xf16,
                                                const unsigned short* __restrict__ wg1t,
                                                const float* __restrict__ bg1,
                                                const float* __restrict__ wg2,
                                                const float* __restrict__ bg2,
                                                float* __restrict__ gs,
                                                int* __restrict__ rcnt,
                                                int* __restrict__ rlist) {
  int bm = blockIdx.x * 128;

  __shared__ __align__(16) unsigned short smem[(1024 + 2048) * 8];  // A 16KB | B 32KB (48KB)
  unsigned short* hs = smem;                    // epilogue: hs[128cols][132]
  float* sc = (float*)&smem[16896];
  float* wg2s = (float*)&smem[20480];

  int tid = threadIdx.x;
  int lane = tid & 63;
  int wid = tid >> 6;                 // 0..7
  int wm = wid >> 2, wn = wid & 3;    // wave tile: 64 rows x 64 cols of 128x256
  int ar = lane & 15, kg = lane >> 4;

  const unsigned short* asrc[2];
  unsigned short* ldsA[2];
#pragma unroll
  for (int q = 0; q < 2; ++q) {
    int cb0 = q * 512 + wid * 64;     // A: 1024 chunks (128 rows x 8)
    int ci = cb0 + lane;
    int row = ci >> 3;
    int cb = (ci & 7) ^ (row & 7);
    asrc[q] = xf16 + (size_t)(bm + row) * DIM + cb * 8;
    ldsA[q] = &smem[cb0 * 8];
  }
  const unsigned short* bsrc[4];
  unsigned short* ldsB[4];
#pragma unroll
  for (int q = 0; q < 4; ++q) {
    int cb0 = q * 512 + wid * 64;     // B: 2048 chunks (256 rows x 8)
    int ci = cb0 + lane;
    int row = ci >> 3;                // 0..255 = h-col
    int cb = (ci & 7) ^ (row & 7);
    bsrc[q] = wg1t + (size_t)row * DIM + cb * 8;
    ldsB[q] = &smem[8192 + cb0 * 8];
  }

  f32x4 acc[4][4] = {};

  for (int kt = 0; kt < DIM / 64; ++kt) {
#pragma unroll
    for (int q = 0; q < 2; ++q) gload_lds16(asrc[q] + kt * 64, ldsA[q]);
#pragma unroll
    for (int q = 0; q < 4; ++q) gload_lds16(bsrc[q] + kt * 64, ldsB[q]);
    __syncthreads();
#pragma unroll
    for (int ks = 0; ks < 2; ++ks) {
      int kc = ks * 4 + kg;
      s16x8 a[4], b[4];
#pragma unroll
      for (int m = 0; m < 4; ++m) {
        int row = wm * 64 + m * 16 + ar;
        a[m] = *(const s16x8*)&smem[row * 64 + ((kc ^ (row & 7)) * 8)];
      }
#pragma unroll
      for (int n = 0; n < 4; ++n) {
        int row = wn * 64 + n * 16 + ar;
        b[n] = *(const s16x8*)&smem[8192 + row * 64 + ((kc ^ (row & 7)) * 8)];
      }
#pragma unroll
      for (int m = 0; m < 4; ++m)
#pragma unroll
        for (int n = 0; n < 4; ++n)
          acc[m][n] = __builtin_amdgcn_mfma_f32_16x16x32_f16(a[m], b[n], acc[m][n], 0, 0, 0);
    }
    __syncthreads();
  }

  // stage Wg2 (8KB fp32) into the dead B-staging tail
#pragma unroll
  for (int j = 0; j < 4; ++j) wg2s[tid * 4 + j] = wg2[tid * 4 + j];

  // per-half: repack relu(h) -> hs[col][tok], then accumulate scores
  int tok2 = (tid & 63) * 2;
  int ex = tid >> 6;                   // expert 0..7
  float s0 = 0.f, s1 = 0.f;
#pragma unroll 1
  for (int half = 0; half < 2; ++half) {
    if ((wn >> 1) == half) {
#pragma unroll
      for (int n = 0; n < 4; ++n) {
        int col = (wn & 1) * 64 + n * 16 + ar;   // 0..127 within half
        float bb = bg1[half * 128 + col];
#pragma unroll
        for (int m = 0; m < 4; ++m) {
          int rbase = wm * 64 + m * 16 + kg * 4;
#pragma unroll
          for (int r = 0; r < 4; ++r)
            hs[col * 132 + rbase + r] = f2h(fmaxf(acc[m][n][r] + bb, 0.f));
        }
      }
    }
    __syncthreads();   // hs (and, first pass, wg2s) visible
#pragma unroll 8
    for (int c = 0; c < 128; ++c) {
      unsigned int pair = *(const unsigned int*)&hs[c * 132 + tok2];
      float h0 = h2f((unsigned short)(pair & 0xffffu));
      float h1 = h2f((unsigned short)(pair >> 16));
      float w = wg2s[(half * 128 + c) * 8 + ex];
      s0 = fmaf(h0, w, s0);
      s1 = fmaf(h1, w, s1);
    }
    __syncthreads();   // done reading hs before next half overwrites
  }

  float b2e = bg2[ex];
  s0 += b2e; s1 += b2e;
  gs[(size_t)(bm + tok2) * 8 + ex] = s0;
  gs[(size_t)(bm + tok2 + 1) * 8 + ex] = s1;
  sc[tok2 * 8 + ex] = s0;
  sc[tok2 * 8 + 8 + ex] = s1;
  __syncthreads();

  // top-3 scan per token; fp16-gate score-gap error sigma ~1e-4; 1e-3 = 10 sigma
  if (tid < 128) {
    float m1 = -3e38f, m2 = -3e38f, m3 = -3e38f;
#pragma unroll
    for (int e = 0; e < 8; ++e) {
      float v = sc[tid * 8 + e];
      if (v > m1)      { m3 = m2; m2 = m1; m1 = v; }
      else if (v > m2) { m3 = m2; m2 = v; }
      else if (v > m3) { m3 = v; }
    }
    if (m2 - m3 < 1e-3f) {
      int i = atomicAdd(rcnt, 1);
      rlist[i] = bm + tid;
    }
  }
}

// ---------------- rescue: exact fp32 gate recompute for flagged tokens ----------------
__global__ __launch_bounds__(256) void k_rescue(const float* __restrict__ x,
                                                const float* __restrict__ wg1,
                                                const float* __restrict__ bg1,
                                                const float* __restrict__ wg2,
                                                const float* __restrict__ bg2,
                                                const int* __restrict__ rcnt,
                                                const int* __restrict__ rlist,
                                                float* __restrict__ gs) {
  __shared__ float xs[DIM];
  __shared__ float ps[4][8];
  int n = rcnt[0];
  int tid = threadIdx.x;
  int lane = tid & 63, wid = tid >> 6;
  for (int idx = blockIdx.x; idx < n; idx += 2048) {
    int tok = rlist[idx];
    __syncthreads();  // protect xs/ps reuse across iterations
#pragma unroll
    for (int q = 0; q < 3; ++q) xs[tid + q * 256] = x[(size_t)tok * DIM + tid + q * 256];
    __syncthreads();
    const float* wcol = wg1 + tid;               // tid = hidden unit (HID==256)
    float pa[8] = {};
#pragma unroll 4
    for (int k0 = 0; k0 < DIM; k0 += 8) {
#pragma unroll
      for (int q = 0; q < 8; ++q)
        pa[q] = fmaf(xs[k0 + q], wcol[(size_t)(k0 + q) * HID], pa[q]);
    }
    float acc = bg1[tid] +
                (((pa[0] + pa[1]) + (pa[2] + pa[3])) + ((pa[4] + pa[5]) + (pa[6] + pa[7])));
    float hj = fmaxf(acc, 0.f);
    float p[8];
#pragma unroll
    for (int e = 0; e < 8; ++e) p[e] = hj * wg2[tid * 8 + e];
#pragma unroll
    for (int off = 32; off >= 1; off >>= 1) {
#pragma unroll
      for (int e = 0; e < 8; ++e) p[e] += __shfl_xor(p[e], off);
    }
    if (lane == 0) {
#pragma unroll
      for (int e = 0; e < 8; ++e) ps[wid][e] = p[e];
    }
    __syncthreads();
    if (tid < 8)
      gs[(size_t)tok * 8 + tid] = bg2[tid] + ps[0][tid] + ps[1][tid] + ps[2][tid] + ps[3][tid];
  }
}

// ---------------- gate 2b: softmax + top2 + routing lists from gs ----------------
__global__ __launch_bounds__(256) void k_gate2b(const float* __restrict__ gs,
                                                float* __restrict__ gprob,
                                                int* __restrict__ cnt,     // stride 32
                                                int* __restrict__ lists,
                                                float* __restrict__ wts) {
  __shared__ int lcnt[8];
  __shared__ int sbase[8];
  __shared__ int se1[256], se2[256], sp1[256], sp2[256];
  __shared__ float sw1[256], sw2[256];
  int tid = threadIdx.x;
  if (tid < 8) lcnt[tid] = 0;
  __syncthreads();

  int tok = blockIdx.x * 256 + tid;
  f32x4 s0v = *(const f32x4*)&gs[(size_t)tok * 8];
  f32x4 s1v = *(const f32x4*)&gs[(size_t)tok * 8 + 4];
  float s[8] = {s0v[0], s0v[1], s0v[2], s0v[3], s1v[0], s1v[1], s1v[2], s1v[3]};

  float m = s[0];
#pragma unroll
  for (int e = 1; e < 8; ++e) m = fmaxf(m, s[e]);
  float p[8]; float sum = 0.f;
#pragma unroll
  for (int e = 0; e < 8; ++e) { p[e] = expf(s[e] - m); sum += p[e]; }
  float inv = 1.f / sum;
#pragma unroll
  for (int e = 0; e < 8; ++e) p[e] *= inv;

  f32x4 o0 = {p[0], p[1], p[2], p[3]};
  f32x4 o1 = {p[4], p[5], p[6], p[7]};
  *(f32x4*)&gprob[(size_t)tok * 8] = o0;
  *(f32x4*)&gprob[(size_t)tok * 8 + 4] = o1;

  int e1 = 0; float p1 = p[0];
#pragma unroll
  for (int e = 1; e < 8; ++e) if (p[e] > p1) { p1 = p[e]; e1 = e; }
  int e2 = -1; float p2 = -1.f;
#pragma unroll
  for (int e = 0; e < 8; ++e) if (e != e1 && p[e] > p2) { p2 = p[e]; e2 = e; }
  float rinv = 1.f / (p1 + p2);

  int pos1 = atomicAdd(&lcnt[e1], 1);
  int pos2 = atomicAdd(&lcnt[e2], 1);
  se1[tid] = e1; sp1[tid] = pos1; sw1[tid] = p1 * rinv;
  se2[tid] = e2; sp2[tid] = pos2; sw2[tid] = p2 * rinv;
  __syncthreads();

  if (tid < 8) sbase[tid] = atomicAdd(&cnt[tid * 32], lcnt[tid]);
  __syncthreads();

  int a1i = sbase[se1[tid]] + sp1[tid];
  lists[se1[tid] * NTOK + a1i] = tok; wts[se1[tid] * NTOK + a1i] = sw1[tid];   // rank0: +w
  int a2i = sbase[se2[tid]] + sp2[tid];
  lists[se2[tid] * NTOK + a2i] = tok; wts[se2[tid] * NTOK + a2i] = -sw2[tid];  // rank1: -w
}

// ---------------- expert layer 1 GEMM (fp16, 512 threads, 128x256 tile) ----------------
__global__ __launch_bounds__(512) void k_ffn1(const unsigned short* __restrict__ xf16,
                                              const unsigned short* __restrict__ w1t,
                                              const float* __restrict__ b1,
                                              const int* __restrict__ cnt,
                                              const int* __restrict__ lists,
                                              unsigned short* __restrict__ h) {
  int id = blockIdx.x;
  int xcd = id & 7, local = id >> 3;
  int xh = local & 31, e = local >> 5;
  int row0 = ((xh << 3) | xcd) * 128;

  int c = cnt[e * 32];
  if (row0 >= c) return;
  int pfx = 0;
#pragma unroll
  for (int j = 0; j < 8; ++j) if (j < e) pfx += cnt[j * 32];

  __shared__ __align__(16) unsigned short smem[(1024 + 2048) * 8];  // A 16KB | B 32KB; repack union
  __shared__ int stok[128];

  int tid = threadIdx.x;
  int lane = tid & 63;
  int wid = tid >> 6;
  int wm = wid >> 2, wn = wid & 3;
  int ar = lane & 15, kg = lane >> 4;

  if (tid < 128) stok[tid] = lists[e * NTOK + min(row0 + tid, c - 1)];
  __syncthreads();

  const unsigned short* asrc[2];
  unsigned short* ldsA[2];
#pragma unroll
  for (int q = 0; q < 2; ++q) {
    int cb0 = q * 512 + wid * 64;
    int ci = cb0 + lane;
    int row = ci >> 3;
    int cb = (ci & 7) ^ (row & 7);
    asrc[q] = xf16 + (size_t)stok[row] * DIM + cb * 8;
    ldsA[q] = &smem[cb0 * 8];
  }
  const unsigned short* bsrc[4];
  unsigned short* ldsB[4];
#pragma unroll
  for (int q = 0; q < 4; ++q) {
    int cb0 = q * 512 + wid * 64;
    int ci = cb0 + lane;
    int row = ci >> 3;
    int cb = (ci & 7) ^ (row & 7);
    bsrc[q] = w1t + ((size_t)e * HID + row) * DIM + cb * 8;
    ldsB[q] = &smem[8192 + cb0 * 8];
  }

  f32x4 acc[4][4] = {};

  for (int kt = 0; kt < DIM / 64; ++kt) {
#pragma unroll
    for (int q = 0; q < 2; ++q) gload_lds16(asrc[q] + kt * 64, ldsA[q]);
#pragma unroll
    for (int q = 0; q < 4; ++q) gload_lds16(bsrc[q] + kt * 64, ldsB[q]);
    __syncthreads();
#pragma unroll
    for (int ks = 0; ks < 2; ++ks) {
      int kc = ks * 4 + kg;
      s16x8 a[4], b[4];
#pragma unroll
      for (int m = 0; m < 4; ++m) {
        int row = wm * 64 + m * 16 + ar;
        a[m] = *(const s16x8*)&smem[row * 64 + ((kc ^ (row & 7)) * 8)];
      }
#pragma unroll
      for (int n = 0; n < 4; ++n) {
        int row = wn * 64 + n * 16 + ar;
        b[n] = *(const s16x8*)&smem[8192 + row * 64 + ((kc ^ (row & 7)) * 8)];
      }
#pragma unroll
      for (int m = 0; m < 4; ++m)
#pragma unroll
        for (int n = 0; n < 4; ++n)
          acc[m][n] = __builtin_amdgcn_mfma_f32_16x16x32_f16(a[m], b[n], acc[m][n], 0, 0, 0);
    }
    __syncthreads();
  }

  // epilogue: two 128-col halves through the 128xPADC repack tile
  int hbase = pfx + row0;
#pragma unroll 1
  for (int half = 0; half < 2; ++half) {
    if ((wn >> 1) == half) {
#pragma unroll
      for (int n = 0; n < 4; ++n) {
        int col = (wn & 1) * 64 + n * 16 + ar;
        float bb = b1[e * HID + half * 128 + col];
#pragma unroll
        for (int m = 0; m < 4; ++m) {
          int rloc = wm * 64 + m * 16 + kg * 4;
#pragma unroll
          for (int r = 0; r < 4; ++r)
            smem[(rloc + r) * PADC + col] = f2h(fmaxf(acc[m][n][r] + bb, 0.f));
        }
      }
    }
    __syncthreads();
#pragma unroll
    for (int q = 0; q < 4; ++q) {
      int ci = tid + q * 512;
      int row = ci >> 4, ch = ci & 15;
      if (row0 + row < c) {
        int4 v = *(const int4*)&smem[row * PADC + ch * 8];
        *(int4*)&h[(size_t)(hbase + row) * HID + half * 128 + ch * 8] = v;
      }
    }
    __syncthreads();
  }
}

// ---------------- expert layer 2 GEMM (fp16, 256 threads, 128x128 tile, 6 panels) ----------------
template <bool STORE_PART>
__global__ __launch_bounds__(256) void k_ffn2(const unsigned short* __restrict__ h,
                                              const unsigned short* __restrict__ w2t,
                                              const float* __restrict__ b2,
                                              const int* __restrict__ cnt,
                                              const int* __restrict__ lists,
                                              const float* __restrict__ wts,
                                              unsigned short* __restrict__ part0,
                                              unsigned short* __restrict__ part1,
                                              float* __restrict__ out) {
  int id = blockIdx.x;
  int xcd = id & 7, local = id >> 3;
  int bny = local % 6;
  int r2 = local / 6;
  int xh = r2 & 31, e = r2 >> 5;
  int row0 = ((xh << 3) | xcd) * 128;
  int bn = bny * 128;

  int c = cnt[e * 32];
  if (row0 >= c) return;
  int pfx = 0;
#pragma unroll
  for (int j = 0; j < 8; ++j) if (j < e) pfx += cnt[j * 32];

  __shared__ __align__(16) unsigned short smem[128 * PADC];  // staging (32KB) U repack tile (36KB)
  __shared__ int stok[128];
  __shared__ float swt[128];
  unsigned short* As = smem;
  unsigned short* Bs = smem + 128 * 64;

  int tid = threadIdx.x;
  int lane = tid & 63;
  int wid = tid >> 6;
  int wm = wid >> 1, wn = wid & 1;
  int ar = lane & 15, kg = lane >> 4;

  if (tid < 128) {
    int r = row0 + tid;
    stok[tid] = (r < c) ? lists[e * NTOK + r] : 0;
    swt[tid]  = (r < c) ? wts[e * NTOK + r] : 0.f;
  }
  __syncthreads();

  const unsigned short* asrc[4];
  const unsigned short* bsrc[4];
  unsigned short* ldsA[4];
  unsigned short* ldsB[4];
#pragma unroll
  for (int i = 0; i < 4; ++i) {
    int cb0 = i * 256 + wid * 64;
    int ci = cb0 + lane;
    int row = ci >> 3;
    int cb = (ci & 7) ^ (row & 7);
    asrc[i] = h + (size_t)(pfx + row0 + row) * HID + cb * 8;
    bsrc[i] = w2t + ((size_t)e * DIM + bn + row) * HID + cb * 8;
    ldsA[i] = &As[cb0 * 8];
    ldsB[i] = &Bs[cb0 * 8];
  }

  f32x4 acc[4][4] = {};

  for (int kt = 0; kt < HID / 64; ++kt) {
#pragma unroll
    for (int i = 0; i < 4; ++i) {
      gload_lds16(asrc[i] + kt * 64, ldsA[i]);
      gload_lds16(bsrc[i] + kt * 64, ldsB[i]);
    }
    __syncthreads();
#pragma unroll
    for (int ks = 0; ks < 2; ++ks) {
      int kc = ks * 4 + kg;
      s16x8 a[4], b[4];
#pragma unroll
      for (int m = 0; m < 4; ++m) {
        int row = wm * 64 + m * 16 + ar;
        a[m] = *(const s16x8*)&As[row * 64 + ((kc ^ (row & 7)) * 8)];
      }
#pragma unroll
      for (int n = 0; n < 4; ++n) {
        int row = wn * 64 + n * 16 + ar;
        b[n] = *(const s16x8*)&Bs[row * 64 + ((kc ^ (row & 7)) * 8)];
      }
#pragma unroll
      for (int m = 0; m < 4; ++m)
#pragma unroll
        for (int n = 0; n < 4; ++n)
          acc[m][n] = __builtin_amdgcn_mfma_f32_16x16x32_f16(a[m], b[n], acc[m][n], 0, 0, 0);
    }
    __syncthreads();
  }

  if constexpr (STORE_PART) {
#pragma unroll
    for (int n = 0; n < 4; ++n) {
      int col = wn * 64 + n * 16 + ar;
      float bb = b2[e * DIM + bn + col];
#pragma unroll
      for (int m = 0; m < 4; ++m) {
        int rloc = wm * 64 + m * 16 + kg * 4;
#pragma unroll
        for (int r = 0; r < 4; ++r) {
          float w = swt[rloc + r];
          smem[(rloc + r) * PADC + col] = f2bf((acc[m][n][r] + bb) * fabsf(w));
        }
      }
    }
    __syncthreads();
#pragma unroll
    for (int q = 0; q < 8; ++q) {
      int ci = tid + q * 256;
      int row = ci >> 4, ch = ci & 15;
      float w = swt[row];
      if (w != 0.f) {
        unsigned short* dst = (w > 0.f) ? part0 : part1;
        int4 v = *(const int4*)&smem[row * PADC + ch * 8];
        *(int4*)&dst[(size_t)stok[row] * DIM + bn + ch * 8] = v;
      }
    }
  } else {
#pragma unroll
    for (int n = 0; n < 4; ++n) {
      int col = bn + wn * 64 + n * 16 + ar;
      float bb = b2[e * DIM + col];
#pragma unroll
      for (int m = 0; m < 4; ++m) {
        int rloc = wm * 64 + m * 16 + kg * 4;
#pragma unroll
        for (int r = 0; r < 4; ++r) {
          float w = swt[rloc + r];
          if (w != 0.f) {
            float v = (acc[m][n][r] + bb) * fabsf(w);
            atomicAdd(&out[(size_t)stok[rloc + r] * DIM + col], v);
          }
        }
      }
    }
  }
}

// ---------------- combine: out = part0 + part1 (streaming) ----------------
__global__ __launch_bounds__(256) void k_combine(const unsigned short* __restrict__ p0,
                                                 const unsigned short* __restrict__ p1,
                                                 float* __restrict__ out) {
  size_t i = ((size_t)blockIdx.x * 256 + threadIdx.x) * 8;
  int4 a = *(const int4*)(p0 + i);
  int4 b = *(const int4*)(p1 + i);
  unsigned int ua[4] = {(unsigned)a.x, (unsigned)a.y, (unsigned)a.z, (unsigned)a.w};
  unsigned int ub[4] = {(unsigned)b.x, (unsigned)b.y, (unsigned)b.z, (unsigned)b.w};
  float o[8];
#pragma unroll
  for (int q = 0; q < 4; ++q) {
    o[q * 2 + 0] = bf2f(ua[q] & 0xffffu) + bf2f(ub[q] & 0xffffu);
    o[q * 2 + 1] = bf2f(ua[q] >> 16)     + bf2f(ub[q] >> 16);
  }
  *(float4*)(out + i)     = *(float4*)&o[0];
  *(float4*)(out + i + 4) = *(float4*)&o[4];
}

extern "C" void kernel_launch(void* const* d_in, const int* in_sizes, int n_in,
                              void* d_out, int out_size, void* d_ws, size_t ws_size,
                              hipStream_t stream) {
  const float* x   = (const float*)d_in[0];
  const float* W1  = (const float*)d_in[1];
  const float* b1  = (const float*)d_in[2];
  const float* W2  = (const float*)d_in[3];
  const float* b2  = (const float*)d_in[4];
  const float* Wg1 = (const float*)d_in[5];
  const float* bg1 = (const float*)d_in[6];
  const float* Wg2 = (const float*)d_in[7];
  const float* bg2 = (const float*)d_in[8];
  float* out = (float*)d_out;                       // [N][768] then [N][8]
  float* gprob = out + (size_t)NTOK * DIM;

  char* ws = (char*)d_ws;
  size_t off = 0;
  auto alloc = [&](size_t bytes) { void* pp = ws + off; off += (bytes + 255) & ~(size_t)255; return pp; };
  unsigned short* w1t = (unsigned short*)alloc((size_t)NEXP * HID * DIM * 2);
  unsigned short* w2t = (unsigned short*)alloc((size_t)NEXP * DIM * HID * 2);
  float* hgbuf = (float*)alloc((size_t)NTOK * HID * 4);   // h (fp16, 32MB)
  int* cnt = (int*)alloc(NEXP * 32 * 4 + 256);      // 128B-padded counters + rcnt tail
  int* lists = (int*)alloc((size_t)NEXP * NTOK * 4);
  float* wts = (float*)alloc((size_t)NEXP * NTOK * 4);
  unsigned short* part0 = (unsigned short*)alloc((size_t)NTOK * DIM * 2);
  unsigned short* part1 = (unsigned short*)alloc((size_t)NTOK * DIM * 2);
  bool store_mode = (off <= ws_size);

  int* rcnt = cnt + NEXP * 32;                       // zeroed by the same memset

  // Gate scratch overlays part0/part1 (written only by k_ffn2/k_combine, which run
  // strictly after every reader of these aliases in stream order). Else: dedicated.
  unsigned short *xf16, *wg1t;
  float* gs; int* rlist;
  if (store_mode) {
    xf16 = part1;                                    // last read by k_ffn1
    wg1t = part0;                                    // [0, 384KB)
    char* p0b = (char*)part0;
    gs    = (float*)(p0b + (1u << 20));              // [1MB, 2MB)
    rlist = (int*)(p0b + 10 * (1u << 18));           // [2.5MB, +128KB)
  } else {
    xf16  = (unsigned short*)alloc((size_t)NTOK * DIM * 2);
    wg1t  = (unsigned short*)alloc((size_t)DIM * HID * 2);
    gs    = (float*)alloc((size_t)NTOK * 8 * 4);
    rlist = (int*)alloc((size_t)NTOK * 4);
  }

  unsigned short* h = (unsigned short*)hgbuf;        // fp16 compact expert hidden (32MB)

  hipMemsetAsync(cnt, 0, NEXP * 32 * sizeof(int) + 256, stream);  // cnt + rcnt in one fill
  if (!store_mode)
    hipMemsetAsync(d_out, 0, (size_t)NTOK * DIM * sizeof(float), stream);

  k_cvt_x<<<(NTOK * DIM) / (256 * 8), 256, 0, stream>>>(x, xf16);
  k_trall<<<dim3(DIM / 32, DIM / 32, 17), 256, 0, stream>>>(W1, Wg1, W2, w1t, wg1t, w2t);
  k_gate1f<<<NTOK / 128, 512, 0, stream>>>(xf16, wg1t, bg1, Wg2, bg2, gs, rcnt, rlist);
  k_rescue<<<2048, 256, 0, stream>>>(x, Wg1, bg1, Wg2, bg2, rcnt, rlist, gs);
  k_gate2b<<<NTOK / 256, 256, 0, stream>>>(gs, gprob, cnt, lists, wts);
  k_ffn1<<<(NTOK / 128) * NEXP, 512, 0, stream>>>(xf16, w1t, b1, cnt, lists, h);
  if (store_mode) {
    k_ffn2<true><<<(NTOK / 128) * 6 * NEXP, 256, 0, stream>>>(h, w2t, b2, cnt, lists, wts, part0, part1, out);
    k_combine<<<(NTOK * DIM) / (256 * 8), 256, 0, stream>>>(part0, part1, out);
  } else {
    k_ffn2<false><<<(NTOK / 128) * 6 * NEXP, 256, 0, stream>>>(h, w2t, b2, cnt, lists, wts, part0, part1, out);
  }
}